// Round 2
// baseline (784.351 us; speedup 1.0000x reference)
//
#include <hip/hip_runtime.h>
#include <stdint.h>

// ArcticDecoderLayer on MI355X (gfx950).
// Precision plan: f16 MFMA everywhere except (a) o-proj GEMM in f16 hi/lo split
// (3 MFMAs) because its error feeds MoE top-k routing, (b) routing itself in
// fp32, (c) RoPE phases in fp64 (matches numpy's float64 promotion).
// R2: attention rewritten — K/V frags straight from global (L2-resident, 1 MB),
// only P in LDS (wave-private strip -> ZERO barriers), 64-row Q tiles (512
// blocks, heavy-first), base-2 softmax, V pre-transposed by vtrans_kernel.
// T=2048 H=1024 NH=16 NKV=4 HD=64 I=2048 E=8 TOPK=2

typedef _Float16 f16;
typedef _Float16 f16x8 __attribute__((ext_vector_type(8)));
typedef _Float16 f16x4 __attribute__((ext_vector_type(4)));
typedef float f32x4 __attribute__((ext_vector_type(4)));

#define DEV __device__ __forceinline__

DEV void glds16(const void* g, void* l) {
  __builtin_amdgcn_global_load_lds((const __attribute__((address_space(1))) void*)g,
                                   (__attribute__((address_space(3))) void*)l, 16, 0, 0);
}

// ---------------- conversions ----------------
__global__ void cvt_f16_kernel(const float* __restrict__ in, f16* __restrict__ outp) {
  const size_t i = ((size_t)blockIdx.x * 256 + threadIdx.x) * 4;
  float4 f = *(const float4*)(in + i);
  f16x4 o;
  o[0] = (f16)f.x; o[1] = (f16)f.y; o[2] = (f16)f.z; o[3] = (f16)f.w;
  *(f16x4*)(outp + i) = o;
}

__global__ void cvt_f16x2_kernel(const float* __restrict__ in,
                                 f16* __restrict__ oh, f16* __restrict__ ol) {
  const size_t i = ((size_t)blockIdx.x * 256 + threadIdx.x) * 4;
  float4 f = *(const float4*)(in + i);
  f16x4 h, l;
  h[0] = (f16)f.x; l[0] = (f16)(f.x - (float)h[0]);
  h[1] = (f16)f.y; l[1] = (f16)(f.y - (float)h[1]);
  h[2] = (f16)f.z; l[2] = (f16)(f.z - (float)h[2]);
  h[3] = (f16)f.w; l[3] = (f16)(f.w - (float)h[3]);
  *(f16x4*)(oh + i) = h;
  *(f16x4*)(ol + i) = l;
}

// ---------------- RMS norms (wave per row, 1024 cols) ----------------
__global__ void rmsnorm_kernel(const float* __restrict__ in, const float* __restrict__ w,
                               f16* __restrict__ outp) {
  const int t = blockIdx.x * 4 + (threadIdx.x >> 6);
  const int lane = threadIdx.x & 63;
  const float* x = in + (size_t)t * 1024;
  float v[16]; float ss = 0.f;
#pragma unroll
  for (int j = 0; j < 16; j++) { float a = x[lane + 64 * j]; v[j] = a; ss += a * a; }
#pragma unroll
  for (int m = 1; m < 64; m <<= 1) ss += __shfl_xor(ss, m);
  const float rs = rsqrtf(ss * (1.f / 1024.f) + 1e-5f);
#pragma unroll
  for (int j = 0; j < 16; j++)
    outp[(size_t)t * 1024 + lane + 64 * j] = (f16)(v[j] * rs * w[lane + 64 * j]);
}

__global__ void rmsnorm_dual_kernel(const float* __restrict__ in,
                                    const float* __restrict__ w1, const float* __restrict__ w2,
                                    f16* __restrict__ o1, f16* __restrict__ o2) {
  const int t = blockIdx.x * 4 + (threadIdx.x >> 6);
  const int lane = threadIdx.x & 63;
  const float* x = in + (size_t)t * 1024;
  float v[16]; float ss = 0.f;
#pragma unroll
  for (int j = 0; j < 16; j++) { float a = x[lane + 64 * j]; v[j] = a; ss += a * a; }
#pragma unroll
  for (int m = 1; m < 64; m <<= 1) ss += __shfl_xor(ss, m);
  const float rs = rsqrtf(ss * (1.f / 1024.f) + 1e-5f);
#pragma unroll
  for (int j = 0; j < 16; j++) {
    float nv = v[j] * rs;
    size_t idx = (size_t)t * 1024 + lane + 64 * j;
    o1[idx] = (f16)(nv * w1[lane + 64 * j]);
    o2[idx] = (f16)(nv * w2[lane + 64 * j]);
  }
}

// ---------------- main GEMM: C[M,N] = A[M,K] * B[N,K]^T, 128x128x32 tiles ----
// EPI: 0 = fp32 store, 1 = fp32 store + addsrc, 2 = f16 store
template <int EPI>
__global__ __launch_bounds__(256) void gemm_f16_kernel(
    const f16* __restrict__ A, const f16* __restrict__ B,
    void* __restrict__ outp, const float* __restrict__ addsrc,
    int M, int N, int K) {
  __shared__ __attribute__((aligned(16))) f16 As[128 * 32];
  __shared__ __attribute__((aligned(16))) f16 Bs[128 * 32];
  const int tid = threadIdx.x;
  const size_t row0 = (size_t)blockIdx.y * 128, col0 = (size_t)blockIdx.x * 128;
  const int c0 = tid, c1 = tid + 256;
  const f16* a0 = A + (row0 + (c0 >> 2)) * K + (c0 & 3) * 8;
  const f16* a1 = A + (row0 + (c1 >> 2)) * K + (c1 & 3) * 8;
  const f16* b0 = B + (col0 + (c0 >> 2)) * K + (c0 & 3) * 8;
  const f16* b1 = B + (col0 + (c1 >> 2)) * K + (c1 & 3) * 8;
  f16 *as0 = As + c0 * 8, *as1 = As + c1 * 8, *bs0 = Bs + c0 * 8, *bs1 = Bs + c1 * 8;

  const int wave = tid >> 6, lane = tid & 63, lr = lane >> 4, lc = lane & 15;
  const int wr = wave >> 1, wc = wave & 1;

  f32x4 acc[4][4];
#pragma unroll
  for (int i = 0; i < 4; i++)
#pragma unroll
    for (int j = 0; j < 4; j++) acc[i][j] = (f32x4){0.f, 0.f, 0.f, 0.f};

  for (int k0 = 0; k0 < K; k0 += 32) {
    glds16(a0 + k0, as0); glds16(a1 + k0, as1);
    glds16(b0 + k0, bs0); glds16(b1 + k0, bs1);
    __syncthreads();
    f16x8 af[4], bfr[4];
#pragma unroll
    for (int i = 0; i < 4; i++)
      af[i] = *(const f16x8*)(As + (wr * 64 + i * 16 + lc) * 32 + lr * 8);
#pragma unroll
    for (int j = 0; j < 4; j++)
      bfr[j] = *(const f16x8*)(Bs + (wc * 64 + j * 16 + lc) * 32 + lr * 8);
#pragma unroll
    for (int i = 0; i < 4; i++)
#pragma unroll
      for (int j = 0; j < 4; j++)
        acc[i][j] = __builtin_amdgcn_mfma_f32_16x16x32_f16(af[i], bfr[j], acc[i][j], 0, 0, 0);
    __syncthreads();
  }

#pragma unroll
  for (int i = 0; i < 4; i++)
#pragma unroll
    for (int j = 0; j < 4; j++) {
      const size_t rbase = row0 + wr * 64 + i * 16 + lr * 4;
      const size_t col = col0 + wc * 64 + j * 16 + lc;
#pragma unroll
      for (int r = 0; r < 4; r++) {
        size_t idx = (rbase + r) * N + col;
        if constexpr (EPI == 0) ((float*)outp)[idx] = acc[i][j][r];
        else if constexpr (EPI == 1) ((float*)outp)[idx] = acc[i][j][r] + addsrc[idx];
        else ((f16*)outp)[idx] = (f16)acc[i][j][r];
      }
    }
}

// ---------------- o-proj GEMM with f16 hi/lo split (3 MFMAs), +residual -----
__global__ __launch_bounds__(256) void gemm_f16x2_add_kernel(
    const f16* __restrict__ Ah, const f16* __restrict__ Al,
    const f16* __restrict__ Bh, const f16* __restrict__ Bl,
    float* __restrict__ outp, const float* __restrict__ addsrc,
    int M, int N, int K) {
  __shared__ __attribute__((aligned(16))) f16 Ash[128 * 32];
  __shared__ __attribute__((aligned(16))) f16 Asl[128 * 32];
  __shared__ __attribute__((aligned(16))) f16 Bsh[128 * 32];
  __shared__ __attribute__((aligned(16))) f16 Bsl[128 * 32];
  const int tid = threadIdx.x;
  const size_t row0 = (size_t)blockIdx.y * 128, col0 = (size_t)blockIdx.x * 128;
  const int c0 = tid, c1 = tid + 256;
  const size_t aoff0 = (row0 + (c0 >> 2)) * K + (c0 & 3) * 8;
  const size_t aoff1 = (row0 + (c1 >> 2)) * K + (c1 & 3) * 8;
  const size_t boff0 = (col0 + (c0 >> 2)) * K + (c0 & 3) * 8;
  const size_t boff1 = (col0 + (c1 >> 2)) * K + (c1 & 3) * 8;

  const int wave = tid >> 6, lane = tid & 63, lr = lane >> 4, lc = lane & 15;
  const int wr = wave >> 1, wc = wave & 1;

  f32x4 acc[4][4];
#pragma unroll
  for (int i = 0; i < 4; i++)
#pragma unroll
    for (int j = 0; j < 4; j++) acc[i][j] = (f32x4){0.f, 0.f, 0.f, 0.f};

  for (int k0 = 0; k0 < K; k0 += 32) {
    glds16(Ah + aoff0 + k0, Ash + c0 * 8); glds16(Ah + aoff1 + k0, Ash + c1 * 8);
    glds16(Al + aoff0 + k0, Asl + c0 * 8); glds16(Al + aoff1 + k0, Asl + c1 * 8);
    glds16(Bh + boff0 + k0, Bsh + c0 * 8); glds16(Bh + boff1 + k0, Bsh + c1 * 8);
    glds16(Bl + boff0 + k0, Bsl + c0 * 8); glds16(Bl + boff1 + k0, Bsl + c1 * 8);
    __syncthreads();
    f16x8 afh[4], afl[4], bfh[4], bfl[4];
#pragma unroll
    for (int i = 0; i < 4; i++) {
      const int ro = (wr * 64 + i * 16 + lc) * 32 + lr * 8;
      afh[i] = *(const f16x8*)(Ash + ro);
      afl[i] = *(const f16x8*)(Asl + ro);
    }
#pragma unroll
    for (int j = 0; j < 4; j++) {
      const int ro = (wc * 64 + j * 16 + lc) * 32 + lr * 8;
      bfh[j] = *(const f16x8*)(Bsh + ro);
      bfl[j] = *(const f16x8*)(Bsl + ro);
    }
#pragma unroll
    for (int i = 0; i < 4; i++)
#pragma unroll
      for (int j = 0; j < 4; j++) {
        acc[i][j] = __builtin_amdgcn_mfma_f32_16x16x32_f16(afh[i], bfh[j], acc[i][j], 0, 0, 0);
        acc[i][j] = __builtin_amdgcn_mfma_f32_16x16x32_f16(afh[i], bfl[j], acc[i][j], 0, 0, 0);
        acc[i][j] = __builtin_amdgcn_mfma_f32_16x16x32_f16(afl[i], bfh[j], acc[i][j], 0, 0, 0);
      }
    __syncthreads();
  }

#pragma unroll
  for (int i = 0; i < 4; i++)
#pragma unroll
    for (int j = 0; j < 4; j++) {
      const size_t rbase = row0 + wr * 64 + i * 16 + lr * 4;
      const size_t col = col0 + wc * 64 + j * 16 + lc;
#pragma unroll
      for (int r = 0; r < 4; r++) {
        size_t idx = (rbase + r) * N + col;
        outp[idx] = acc[i][j][r] + addsrc[idx];
      }
    }
}

// ---------------- MoE GEMM: gathered A rows via perm, per-expert B -----------
// DIVROW=1: A row = sid>>1 (token) ; DIVROW=0: A row = sid (slot)
template <int DIVROW>
__global__ __launch_bounds__(256) void gemm_moe_kernel(
    const f16* __restrict__ A, const f16* __restrict__ Ball, f16* __restrict__ outp,
    const int* __restrict__ perm, const int* __restrict__ counts,
    int N, int K, size_t strideB) {
  const int e = blockIdx.z;
  const int cnt = counts[e];
  const int bm = blockIdx.y;
  if (bm * 128 >= cnt) return;
  const f16* B = Ball + (size_t)e * strideB;
  __shared__ __attribute__((aligned(16))) f16 As[128 * 32];
  __shared__ __attribute__((aligned(16))) f16 Bs[128 * 32];
  const int tid = threadIdx.x;
  const size_t col0 = (size_t)blockIdx.x * 128;
  const int c0 = tid, c1 = tid + 256;
  const int pbase = e * 2048 + bm * 128;
  const int rt0 = c0 >> 2, rt1 = c1 >> 2;
  const int sid0 = (bm * 128 + rt0 < cnt) ? perm[pbase + rt0] : -1;
  const int sid1 = (bm * 128 + rt1 < cnt) ? perm[pbase + rt1] : -1;
  const size_t ar0 = DIVROW ? (size_t)(sid0 >> 1) : (size_t)sid0;
  const size_t ar1 = DIVROW ? (size_t)(sid1 >> 1) : (size_t)sid1;
  const f16* ap0 = A + ar0 * K + (c0 & 3) * 8;
  const f16* ap1 = A + ar1 * K + (c1 & 3) * 8;
  const f16* b0 = B + (col0 + (c0 >> 2)) * K + (c0 & 3) * 8;
  const f16* b1 = B + (col0 + (c1 >> 2)) * K + (c1 & 3) * 8;

  const int wave = tid >> 6, lane = tid & 63, lr = lane >> 4, lc = lane & 15;
  const int wr = wave >> 1, wc = wave & 1;

  f32x4 acc[4][4];
#pragma unroll
  for (int i = 0; i < 4; i++)
#pragma unroll
    for (int j = 0; j < 4; j++) acc[i][j] = (f32x4){0.f, 0.f, 0.f, 0.f};

  for (int k0 = 0; k0 < K; k0 += 32) {
    glds16(b0 + k0, Bs + c0 * 8);
    glds16(b1 + k0, Bs + c1 * 8);
    f16x8 va0, va1;
#pragma unroll
    for (int x = 0; x < 8; x++) { va0[x] = (f16)0.f; va1[x] = (f16)0.f; }
    if (sid0 >= 0) va0 = *(const f16x8*)(ap0 + k0);
    if (sid1 >= 0) va1 = *(const f16x8*)(ap1 + k0);
    *(f16x8*)(As + c0 * 8) = va0;
    *(f16x8*)(As + c1 * 8) = va1;
    __syncthreads();
    f16x8 af[4], bfr[4];
#pragma unroll
    for (int i = 0; i < 4; i++)
      af[i] = *(const f16x8*)(As + (wr * 64 + i * 16 + lc) * 32 + lr * 8);
#pragma unroll
    for (int j = 0; j < 4; j++)
      bfr[j] = *(const f16x8*)(Bs + (wc * 64 + j * 16 + lc) * 32 + lr * 8);
#pragma unroll
    for (int i = 0; i < 4; i++)
#pragma unroll
      for (int j = 0; j < 4; j++)
        acc[i][j] = __builtin_amdgcn_mfma_f32_16x16x32_f16(af[i], bfr[j], acc[i][j], 0, 0, 0);
    __syncthreads();
  }

  int sids[4][4];
#pragma unroll
  for (int i = 0; i < 4; i++)
#pragma unroll
    for (int r = 0; r < 4; r++) {
      int rit = wr * 64 + i * 16 + lr * 4 + r;
      sids[i][r] = (bm * 128 + rit < cnt) ? perm[pbase + rit] : -1;
    }
#pragma unroll
  for (int i = 0; i < 4; i++)
#pragma unroll
    for (int j = 0; j < 4; j++) {
      const size_t col = col0 + wc * 64 + j * 16 + lc;
#pragma unroll
      for (int r = 0; r < 4; r++)
        if (sids[i][r] >= 0)
          outp[(size_t)sids[i][r] * N + col] = (f16)acc[i][j][r];
    }
}

// ---------------- RoPE (fp64 phases), q scaled by HD^-0.5 * log2(e) ---------
__global__ void rope_kernel(const float* __restrict__ qkv, const int* __restrict__ pos,
                            f16* __restrict__ qr, f16* __restrict__ kr) {
  const int t = blockIdx.y;
  const int u = blockIdx.x * 256 + threadIdx.x;  // 0..767, use 0..639
  if (u >= 640) return;
  const float* base = qkv + (size_t)t * 1536;
  const int head = u >> 5, i = u & 31;
  const bool isq = head < 16;
  const int off = isq ? head * 64 + i : 1024 + (head - 16) * 64 + i;
  const float x1 = base[off], x2 = base[off + 32];
  const double ph = (double)pos[t] * exp((double)i * -0.28782313662425575);  // ln(1e4)/32
  const float c = (float)cos(ph), s = (float)sin(ph);
  const float r1 = x1 * c - x2 * s, r2 = x2 * c + x1 * s;
  if (isq) {
    // 0.125 * log2(e): base-2 softmax in attn
    const float qs = 0.18033688011116042f;
    qr[(size_t)t * 1024 + head * 64 + i] = (f16)(qs * r1);
    qr[(size_t)t * 1024 + head * 64 + i + 32] = (f16)(qs * r2);
  } else {
    const int kh = head - 16;
    kr[(size_t)t * 256 + kh * 64 + i] = (f16)r1;
    kr[(size_t)t * 256 + kh * 64 + i + 32] = (f16)r2;
  }
}

// ---------------- V transpose: qkvf[t][1280+kv*64+d] -> vt[kv*64+d][t] ------
__global__ void vtrans_kernel(const float* __restrict__ qkvf, f16* __restrict__ vt) {
  __shared__ float Ts[64 * 69];
  const int t0 = blockIdx.x * 64;
  const int kv = blockIdx.y;
  const int tid = threadIdx.x;
  const int tr = tid >> 2, jj = tid & 3;
  const float* src = qkvf + (size_t)(t0 + tr) * 1536 + 1280 + kv * 64 + jj * 16;
#pragma unroll
  for (int x = 0; x < 4; x++) {
    float4 f = *(const float4*)(src + x * 4);
    Ts[tr * 69 + jj * 16 + x * 4 + 0] = f.x;
    Ts[tr * 69 + jj * 16 + x * 4 + 1] = f.y;
    Ts[tr * 69 + jj * 16 + x * 4 + 2] = f.z;
    Ts[tr * 69 + jj * 16 + x * 4 + 3] = f.w;
  }
  __syncthreads();
  f16* dst = vt + (size_t)(kv * 64 + tr) * 2048 + t0 + jj * 16;
#pragma unroll
  for (int x = 0; x < 2; x++) {
    f16x8 o;
#pragma unroll
    for (int i = 0; i < 8; i++) o[i] = (f16)Ts[(jj * 16 + x * 8 + i) * 69 + tr];
    *(f16x8*)(dst + x * 8) = o;
  }
}

// ---------------- flash attention v2: 64-row Q tiles, K/V from global -------
// No barriers: Ps strips are wave-private; K/V frag gathers hit L1/L2 (1 MB set).
__global__ __launch_bounds__(256) void attn_kernel(
    const f16* __restrict__ qr, const f16* __restrict__ kr, const f16* __restrict__ vt,
    f16* __restrict__ ahi, f16* __restrict__ alo) {
  const int qt = 31 - blockIdx.x;  // heavy tiles first
  const int h = blockIdx.y;
  const int kvh = h >> 2;
  __shared__ __attribute__((aligned(16))) f16 Ps[64 * 136];  // pad 136: 2-way only
  const int tid = threadIdx.x;
  const int wave = tid >> 6, lane = tid & 63, lr = lane >> 4, lc = lane & 15;
  const int qrow0 = qt * 64 + wave * 16;

  f16x8 qf[2];
#pragma unroll
  for (int kki = 0; kki < 2; kki++)
    qf[kki] = *(const f16x8*)(qr + (size_t)(qrow0 + lc) * 1024 + h * 64 + kki * 32 + lr * 8);

  float mst[4], lst[4];
  f32x4 accO[4];
#pragma unroll
  for (int r = 0; r < 4; r++) { mst[r] = -3e38f; lst[r] = 0.f; }
#pragma unroll
  for (int jo = 0; jo < 4; jo++) accO[jo] = (f32x4){0.f, 0.f, 0.f, 0.f};

  const int nst = (qt >> 1) + 1;
  const f16* kp = kr + kvh * 64 + lr * 8;
  const f16* vp = vt + ((size_t)kvh * 64) * 2048 + lr * 8;

  for (int st = 0; st < nst; ++st) {
    // ---- QK^T: K frags straight from global (stride-256B gather, L1/L2) ----
    f32x4 sa[8];
#pragma unroll
    for (int j = 0; j < 8; j++) sa[j] = (f32x4){0.f, 0.f, 0.f, 0.f};
#pragma unroll
    for (int j = 0; j < 8; j++) {
      const f16* kb = kp + (size_t)(st * 128 + j * 16 + lc) * 256;
      f16x8 bk0 = *(const f16x8*)(kb);
      f16x8 bk1 = *(const f16x8*)(kb + 32);
      sa[j] = __builtin_amdgcn_mfma_f32_16x16x32_f16(qf[0], bk0, sa[j], 0, 0, 0);
      sa[j] = __builtin_amdgcn_mfma_f32_16x16x32_f16(qf[1], bk1, sa[j], 0, 0, 0);
    }

    // ---- base-2 online softmax ----
    const bool last = (st == nst - 1);
#pragma unroll
    for (int r = 0; r < 4; r++) {
      const int prow = wave * 16 + lr * 4 + r;
      const int rg = qt * 64 + prow;
      float vm = -3e38f;
#pragma unroll
      for (int j = 0; j < 8; j++) {
        float s = sa[j][r];
        if (last && (st * 128 + j * 16 + lc) > rg) s = -3e38f;
        sa[j][r] = s;
        vm = fmaxf(vm, s);
      }
      vm = fmaxf(vm, __shfl_xor(vm, 1));
      vm = fmaxf(vm, __shfl_xor(vm, 2));
      vm = fmaxf(vm, __shfl_xor(vm, 4));
      vm = fmaxf(vm, __shfl_xor(vm, 8));
      const float mn = fmaxf(mst[r], vm);
      const float alpha = __builtin_amdgcn_exp2f(mst[r] - mn);
      mst[r] = mn;
      float rsum = 0.f;
#pragma unroll
      for (int j = 0; j < 8; j++) {
        float pv = __builtin_amdgcn_exp2f(sa[j][r] - mn);
        rsum += pv;
        Ps[prow * 136 + j * 16 + lc] = (f16)pv;
      }
      rsum += __shfl_xor(rsum, 1);
      rsum += __shfl_xor(rsum, 2);
      rsum += __shfl_xor(rsum, 4);
      rsum += __shfl_xor(rsum, 8);
      lst[r] = lst[r] * alpha + rsum;
#pragma unroll
      for (int jo = 0; jo < 4; jo++) accO[jo][r] *= alpha;
    }

    // ---- P·V: P from wave-private LDS strip, V^T frags from global ----
#pragma unroll
    for (int kkt = 0; kkt < 4; kkt++) {
      f16x8 pa = *(const f16x8*)(Ps + (wave * 16 + lc) * 136 + kkt * 32 + lr * 8);
#pragma unroll
      for (int jo = 0; jo < 4; jo++) {
        f16x8 bv = *(const f16x8*)(vp + (size_t)(jo * 16 + lc) * 2048 + st * 128 + kkt * 32);
        accO[jo] = __builtin_amdgcn_mfma_f32_16x16x32_f16(pa, bv, accO[jo], 0, 0, 0);
      }
    }
  }

#pragma unroll
  for (int r = 0; r < 4; r++) {
    const float inv = 1.f / lst[r];
    const size_t row = (size_t)qrow0 + lr * 4 + r;
#pragma unroll
    for (int jo = 0; jo < 4; jo++) {
      float o = accO[jo][r] * inv;
      f16 hi = (f16)o;
      size_t idx = row * 1024 + h * 64 + jo * 16 + lc;
      ahi[idx] = hi;
      alo[idx] = (f16)(o - (float)hi);
    }
  }
}

// ---------------- routing: fp32 norm + gate + top2, compaction --------------
__global__ void routing_kernel(const float* __restrict__ resA,
                               const float* __restrict__ postw,
                               const float* __restrict__ gw,
                               int* __restrict__ counts, int* __restrict__ perm,
                               float* __restrict__ rw) {
  const int t = blockIdx.x * 4 + (threadIdx.x >> 6);
  const int lane = threadIdx.x & 63;
  const float* x = resA + (size_t)t * 1024;
  float v[16]; float ss = 0.f;
#pragma unroll
  for (int j = 0; j < 16; j++) { float a = x[lane + 64 * j]; v[j] = a; ss += a * a; }
#pragma unroll
  for (int m = 1; m < 64; m <<= 1) ss += __shfl_xor(ss, m);
  const float rs = rsqrtf(ss * (1.f / 1024.f) + 1e-5f);
#pragma unroll
  for (int j = 0; j < 16; j++) v[j] *= rs * postw[lane + 64 * j];
  float lg[8];
#pragma unroll
  for (int e = 0; e < 8; e++) {
    float p = 0.f;
    const float* g = gw + (size_t)e * 1024;
#pragma unroll
    for (int j = 0; j < 16; j++) p += v[j] * g[lane + 64 * j];
#pragma unroll
    for (int m = 1; m < 64; m <<= 1) p += __shfl_xor(p, m);
    lg[e] = p;
  }
  if (lane == 0) {
    int e0 = 0; float b0 = lg[0];
#pragma unroll
    for (int e = 1; e < 8; e++) if (lg[e] > b0) { b0 = lg[e]; e0 = e; }
    int e1 = -1; float b1 = -3e38f;
#pragma unroll
    for (int e = 0; e < 8; e++) if (e != e0 && lg[e] > b1) { b1 = lg[e]; e1 = e; }
    const float w0 = 1.f / (1.f + expf(b1 - b0));  // p0/(p0+p1)
    const float w1 = 1.f - w0;
    int p0 = atomicAdd(&counts[e0], 1);
    perm[e0 * 2048 + p0] = t * 2;
    int p1 = atomicAdd(&counts[e1], 1);
    perm[e1 * 2048 + p1] = t * 2 + 1;
    rw[t * 2] = w0;
    rw[t * 2 + 1] = w1;
  }
}

// ---------------- silu(g)*u ----------------
__global__ void silu_mul_kernel(const f16* __restrict__ gu, f16* __restrict__ outp, int lgN) {
  const int N = 1 << lgN;
  const size_t i4 = ((size_t)blockIdx.x * 256 + threadIdx.x) * 4;
  const size_t r = i4 >> lgN;
  const int c = (int)(i4 & (N - 1));
  const f16* gp = gu + r * (size_t)(2 * N) + c;
  f16x4 g = *(const f16x4*)gp;
  f16x4 u = *(const f16x4*)(gp + N);
  f16x4 o;
#pragma unroll
  for (int x = 0; x < 4; x++) {
    float gg = (float)g[x], uu = (float)u[x];
    o[x] = (f16)(gg / (1.f + __expf(-gg)) * uu);
  }
  *(f16x4*)(outp + r * (size_t)N + c) = o;
}

// ---------------- final: out += w0*eo[2t] + w1*eo[2t+1] ----------------
__global__ void final_add_kernel(float* __restrict__ outp, const f16* __restrict__ eo,
                                 const float* __restrict__ rw) {
  const size_t i4 = ((size_t)blockIdx.x * 256 + threadIdx.x) * 4;
  const int t = (int)(i4 >> 10);
  const int c = (int)(i4 & 1023);
  const float w0 = rw[2 * t], w1 = rw[2 * t + 1];
  f16x4 a = *(const f16x4*)(eo + ((size_t)(2 * t)) * 1024 + c);
  f16x4 b = *(const f16x4*)(eo + ((size_t)(2 * t + 1)) * 1024 + c);
  float4 o = *(float4*)(outp + i4);
  o.x += w0 * (float)a[0] + w1 * (float)b[0];
  o.y += w0 * (float)a[1] + w1 * (float)b[1];
  o.z += w0 * (float)a[2] + w1 * (float)b[2];
  o.w += w0 * (float)a[3] + w1 * (float)b[3];
  *(float4*)(outp + i4) = o;
}

extern "C" void kernel_launch(void* const* d_in, const int* in_sizes, int n_in,
                              void* d_out, int out_size, void* d_ws, size_t ws_size,
                              hipStream_t stream) {
  const int* positions = (const int*)d_in[0];
  const float* hidden = (const float*)d_in[1];
  const float* in_ln = (const float*)d_in[2];
  const float* post_ln = (const float*)d_in[3];
  const float* res_ln = (const float*)d_in[4];
  const float* qkv_w = (const float*)d_in[5];
  const float* o_w = (const float*)d_in[6];
  const float* gate_w = (const float*)d_in[7];
  const float* ws_w = (const float*)d_in[8];
  const float* w2s_w = (const float*)d_in[9];
  const float* w13_w = (const float*)d_in[10];
  const float* w2_w = (const float*)d_in[11];
  float* out = (float*)d_out;

  char* p = (char*)d_ws;
  auto alloc = [&](size_t b) { void* r = (void*)p; p += (b + 255) & ~(size_t)255; return r; };

  f16* wqkv = (f16*)alloc((size_t)1536 * 1024 * 2);
  f16* woh  = (f16*)alloc((size_t)1024 * 1024 * 2);
  f16* wol  = (f16*)alloc((size_t)1024 * 1024 * 2);
  f16* wws  = (f16*)alloc((size_t)8 * 4096 * 1024 * 2);
  f16* ww2  = (f16*)alloc((size_t)8 * 1024 * 2048 * 2);
  f16* w13  = (f16*)alloc((size_t)2048 * 1024 * 2);
  f16* w2c  = (f16*)alloc((size_t)1024 * 1024 * 2);
  f16* hn   = (f16*)alloc((size_t)2048 * 1024 * 2);
  float* qkvf = (float*)alloc((size_t)2048 * 1536 * 4);
  f16* qr = (f16*)alloc((size_t)2048 * 1024 * 2);
  f16* kr = (f16*)alloc((size_t)2048 * 256 * 2);
  f16* vt = (f16*)alloc((size_t)256 * 2048 * 2);
  f16* ath = (f16*)alloc((size_t)2048 * 1024 * 2);
  f16* atl = (f16*)alloc((size_t)2048 * 1024 * 2);
  float* resA = (float*)alloc((size_t)2048 * 1024 * 4);
  f16* rn = (f16*)alloc((size_t)2048 * 1024 * 2);
  f16* mn = (f16*)alloc((size_t)2048 * 1024 * 2);
  f16* gu13 = (f16*)alloc((size_t)2048 * 2048 * 2);
  f16* act13 = (f16*)alloc((size_t)2048 * 1024 * 2);
  f16* gum = (f16*)alloc((size_t)4096 * 4096 * 2);
  f16* actm = (f16*)alloc((size_t)4096 * 2048 * 2);
  f16* eo = (f16*)alloc((size_t)4096 * 1024 * 2);
  float* rw = (float*)alloc((size_t)4096 * 4);
  int* counts = (int*)alloc(256);
  int* perm = (int*)alloc((size_t)8 * 2048 * 4);

  // weight conversions (ws is re-poisoned before every timed launch)
  cvt_f16_kernel<<<dim3(1536 * 1024 / 1024), dim3(256), 0, stream>>>(qkv_w, wqkv);
  cvt_f16_kernel<<<dim3(8 * 4096 * 1024 / 1024), dim3(256), 0, stream>>>(ws_w, wws);
  cvt_f16_kernel<<<dim3(8 * 1024 * 2048 / 1024), dim3(256), 0, stream>>>(w2s_w, ww2);
  cvt_f16_kernel<<<dim3(2048 * 1024 / 1024), dim3(256), 0, stream>>>(w13_w, w13);
  cvt_f16_kernel<<<dim3(1024 * 1024 / 1024), dim3(256), 0, stream>>>(w2_w, w2c);
  cvt_f16x2_kernel<<<dim3(1024 * 1024 / 1024), dim3(256), 0, stream>>>(o_w, woh, wol);
  hipMemsetAsync(counts, 0, 256, stream);

  // attention path
  rmsnorm_kernel<<<dim3(512), dim3(256), 0, stream>>>(hidden, in_ln, hn);
  gemm_f16_kernel<0><<<dim3(12, 16), dim3(256), 0, stream>>>(
      hn, wqkv, (void*)qkvf, (const float*)nullptr, 2048, 1536, 1024);
  rope_kernel<<<dim3(3, 2048), dim3(256), 0, stream>>>(qkvf, positions, qr, kr);
  vtrans_kernel<<<dim3(32, 4), dim3(256), 0, stream>>>(qkvf, vt);
  attn_kernel<<<dim3(32, 16), dim3(256), 0, stream>>>(qr, kr, vt, ath, atl);
  gemm_f16x2_add_kernel<<<dim3(8, 16), dim3(256), 0, stream>>>(
      ath, atl, woh, wol, resA, hidden, 2048, 1024, 1024);

  // norms + routing off residual_attn
  rmsnorm_dual_kernel<<<dim3(512), dim3(256), 0, stream>>>(resA, res_ln, post_ln, rn, mn);
  routing_kernel<<<dim3(512), dim3(256), 0, stream>>>(resA, post_ln, gate_w, counts, perm, rw);

  // residual MLP -> d_out holds residual_mlp
  gemm_f16_kernel<2><<<dim3(16, 16), dim3(256), 0, stream>>>(
      rn, w13, (void*)gu13, (const float*)nullptr, 2048, 2048, 1024);
  silu_mul_kernel<<<dim3(2048 * 1024 / 1024), dim3(256), 0, stream>>>(gu13, act13, 10);
  gemm_f16_kernel<1><<<dim3(8, 16), dim3(256), 0, stream>>>(
      act13, w2c, (void*)out, resA, 2048, 1024, 1024);

  // MoE (top-2 sparse)
  gemm_moe_kernel<1><<<dim3(32, 16, 8), dim3(256), 0, stream>>>(
      mn, wws, gum, perm, counts, 4096, 1024, (size_t)4096 * 1024);
  silu_mul_kernel<<<dim3(4096 * 2048 / 1024), dim3(256), 0, stream>>>(gum, actm, 11);
  gemm_moe_kernel<0><<<dim3(8, 16, 8), dim3(256), 0, stream>>>(
      actm, ww2, eo, perm, counts, 1024, 2048, (size_t)1024 * 2048);
  final_add_kernel<<<dim3(2048 * 1024 / 1024), dim3(256), 0, stream>>>(out, eo, rw);
}

// Round 3
// 767.454 us; speedup vs baseline: 1.0220x; 1.0220x over previous
//
#include <hip/hip_runtime.h>
#include <stdint.h>

// ArcticDecoderLayer on MI355X (gfx950).
// Precision plan: f16 MFMA everywhere except (a) o-proj GEMM in f16 hi/lo split
// (3 MFMAs) because its error feeds MoE top-k routing, (b) routing itself in
// fp32, (c) RoPE phases in fp64 (matches numpy's float64 promotion).
// R3: attention computes S^T = K*Q^T so softmax reduces in-lane over regs
// (2 shuffles per 256-chunk instead of 32 per 128-step), P^T via packed b64
// LDS writes, O^T = V^T*P^T. 1-wave blocks (16 q-rows), heavy-first, no
// barriers. Small-grid GEMMs get 128x64 tiles for 2x CU coverage.
// T=2048 H=1024 NH=16 NKV=4 HD=64 I=2048 E=8 TOPK=2

typedef _Float16 f16;
typedef _Float16 f16x8 __attribute__((ext_vector_type(8)));
typedef _Float16 f16x4 __attribute__((ext_vector_type(4)));
typedef float f32x4 __attribute__((ext_vector_type(4)));

#define DEV __device__ __forceinline__

DEV void glds16(const void* g, void* l) {
  __builtin_amdgcn_global_load_lds((const __attribute__((address_space(1))) void*)g,
                                   (__attribute__((address_space(3))) void*)l, 16, 0, 0);
}

// ---------------- conversions ----------------
__global__ void cvt_f16_kernel(const float* __restrict__ in, f16* __restrict__ outp) {
  const size_t i = ((size_t)blockIdx.x * 256 + threadIdx.x) * 4;
  float4 f = *(const float4*)(in + i);
  f16x4 o;
  o[0] = (f16)f.x; o[1] = (f16)f.y; o[2] = (f16)f.z; o[3] = (f16)f.w;
  *(f16x4*)(outp + i) = o;
}

__global__ void cvt_f16x2_kernel(const float* __restrict__ in,
                                 f16* __restrict__ oh, f16* __restrict__ ol) {
  const size_t i = ((size_t)blockIdx.x * 256 + threadIdx.x) * 4;
  float4 f = *(const float4*)(in + i);
  f16x4 h, l;
  h[0] = (f16)f.x; l[0] = (f16)(f.x - (float)h[0]);
  h[1] = (f16)f.y; l[1] = (f16)(f.y - (float)h[1]);
  h[2] = (f16)f.z; l[2] = (f16)(f.z - (float)h[2]);
  h[3] = (f16)f.w; l[3] = (f16)(f.w - (float)h[3]);
  *(f16x4*)(oh + i) = h;
  *(f16x4*)(ol + i) = l;
}

// ---------------- RMS norms (wave per row, 1024 cols) ----------------
__global__ void rmsnorm_kernel(const float* __restrict__ in, const float* __restrict__ w,
                               f16* __restrict__ outp) {
  const int t = blockIdx.x * 4 + (threadIdx.x >> 6);
  const int lane = threadIdx.x & 63;
  const float* x = in + (size_t)t * 1024;
  float v[16]; float ss = 0.f;
#pragma unroll
  for (int j = 0; j < 16; j++) { float a = x[lane + 64 * j]; v[j] = a; ss += a * a; }
#pragma unroll
  for (int m = 1; m < 64; m <<= 1) ss += __shfl_xor(ss, m);
  const float rs = rsqrtf(ss * (1.f / 1024.f) + 1e-5f);
#pragma unroll
  for (int j = 0; j < 16; j++)
    outp[(size_t)t * 1024 + lane + 64 * j] = (f16)(v[j] * rs * w[lane + 64 * j]);
}

__global__ void rmsnorm_dual_kernel(const float* __restrict__ in,
                                    const float* __restrict__ w1, const float* __restrict__ w2,
                                    f16* __restrict__ o1, f16* __restrict__ o2) {
  const int t = blockIdx.x * 4 + (threadIdx.x >> 6);
  const int lane = threadIdx.x & 63;
  const float* x = in + (size_t)t * 1024;
  float v[16]; float ss = 0.f;
#pragma unroll
  for (int j = 0; j < 16; j++) { float a = x[lane + 64 * j]; v[j] = a; ss += a * a; }
#pragma unroll
  for (int m = 1; m < 64; m <<= 1) ss += __shfl_xor(ss, m);
  const float rs = rsqrtf(ss * (1.f / 1024.f) + 1e-5f);
#pragma unroll
  for (int j = 0; j < 16; j++) {
    float nv = v[j] * rs;
    size_t idx = (size_t)t * 1024 + lane + 64 * j;
    o1[idx] = (f16)(nv * w1[lane + 64 * j]);
    o2[idx] = (f16)(nv * w2[lane + 64 * j]);
  }
}

// ---------------- main GEMM: C[M,N] = A[M,K] * B[N,K]^T, 128xBN x32 tiles ----
// EPI: 0 = fp32 store, 1 = fp32 store + addsrc, 2 = f16 store
template <int EPI, int BN>
__global__ __launch_bounds__(256) void gemm_f16_kernel(
    const f16* __restrict__ A, const f16* __restrict__ B,
    void* __restrict__ outp, const float* __restrict__ addsrc,
    int M, int N, int K) {
  constexpr int JT = BN / 32;  // col fragments per wave (wave covers BN/2 cols)
  __shared__ __attribute__((aligned(16))) f16 As[128 * 32];
  __shared__ __attribute__((aligned(16))) f16 Bs[BN * 32];
  const int tid = threadIdx.x;
  const size_t row0 = (size_t)blockIdx.y * 128, col0 = (size_t)blockIdx.x * BN;
  const int c0 = tid, c1 = tid + 256;
  const f16* a0 = A + (row0 + (c0 >> 2)) * K + (c0 & 3) * 8;
  const f16* a1 = A + (row0 + (c1 >> 2)) * K + (c1 & 3) * 8;
  const f16* b0 = B + (col0 + (c0 >> 2)) * K + (c0 & 3) * 8;
  const f16* b1 = B + (col0 + ((BN == 128) ? (c1 >> 2) : 0)) * K + (c1 & 3) * 8;

  const int wave = tid >> 6, lane = tid & 63, lr = lane >> 4, lc = lane & 15;
  const int wr = wave >> 1, wc = wave & 1;

  f32x4 acc[4][JT];
#pragma unroll
  for (int i = 0; i < 4; i++)
#pragma unroll
    for (int j = 0; j < JT; j++) acc[i][j] = (f32x4){0.f, 0.f, 0.f, 0.f};

  for (int k0 = 0; k0 < K; k0 += 32) {
    glds16(a0 + k0, As + c0 * 8); glds16(a1 + k0, As + c1 * 8);
    glds16(b0 + k0, Bs + c0 * 8);
    if constexpr (BN == 128) glds16(b1 + k0, Bs + c1 * 8);
    __syncthreads();
    f16x8 af[4], bfr[JT];
#pragma unroll
    for (int i = 0; i < 4; i++)
      af[i] = *(const f16x8*)(As + (wr * 64 + i * 16 + lc) * 32 + lr * 8);
#pragma unroll
    for (int j = 0; j < JT; j++)
      bfr[j] = *(const f16x8*)(Bs + (wc * (BN / 2) + j * 16 + lc) * 32 + lr * 8);
#pragma unroll
    for (int i = 0; i < 4; i++)
#pragma unroll
      for (int j = 0; j < JT; j++)
        acc[i][j] = __builtin_amdgcn_mfma_f32_16x16x32_f16(af[i], bfr[j], acc[i][j], 0, 0, 0);
    __syncthreads();
  }

#pragma unroll
  for (int i = 0; i < 4; i++)
#pragma unroll
    for (int j = 0; j < JT; j++) {
      const size_t rbase = row0 + wr * 64 + i * 16 + lr * 4;
      const size_t col = col0 + wc * (BN / 2) + j * 16 + lc;
#pragma unroll
      for (int r = 0; r < 4; r++) {
        size_t idx = (rbase + r) * N + col;
        if constexpr (EPI == 0) ((float*)outp)[idx] = acc[i][j][r];
        else if constexpr (EPI == 1) ((float*)outp)[idx] = acc[i][j][r] + addsrc[idx];
        else ((f16*)outp)[idx] = (f16)acc[i][j][r];
      }
    }
}

// ---------------- o-proj GEMM, f16 hi/lo split (3 MFMAs), +residual, 128x64 -
__global__ __launch_bounds__(256) void gemm_f16x2_add_kernel(
    const f16* __restrict__ Ah, const f16* __restrict__ Al,
    const f16* __restrict__ Bh, const f16* __restrict__ Bl,
    float* __restrict__ outp, const float* __restrict__ addsrc,
    int M, int N, int K) {
  __shared__ __attribute__((aligned(16))) f16 Ash[128 * 32];
  __shared__ __attribute__((aligned(16))) f16 Asl[128 * 32];
  __shared__ __attribute__((aligned(16))) f16 Bsh[64 * 32];
  __shared__ __attribute__((aligned(16))) f16 Bsl[64 * 32];
  const int tid = threadIdx.x;
  const size_t row0 = (size_t)blockIdx.y * 128, col0 = (size_t)blockIdx.x * 64;
  const int c0 = tid, c1 = tid + 256;
  const size_t aoff0 = (row0 + (c0 >> 2)) * K + (c0 & 3) * 8;
  const size_t aoff1 = (row0 + (c1 >> 2)) * K + (c1 & 3) * 8;
  const size_t boff0 = (col0 + (c0 >> 2)) * K + (c0 & 3) * 8;

  const int wave = tid >> 6, lane = tid & 63, lr = lane >> 4, lc = lane & 15;
  const int wr = wave >> 1, wc = wave & 1;

  f32x4 acc[4][2];
#pragma unroll
  for (int i = 0; i < 4; i++)
#pragma unroll
    for (int j = 0; j < 2; j++) acc[i][j] = (f32x4){0.f, 0.f, 0.f, 0.f};

  for (int k0 = 0; k0 < K; k0 += 32) {
    glds16(Ah + aoff0 + k0, Ash + c0 * 8); glds16(Ah + aoff1 + k0, Ash + c1 * 8);
    glds16(Al + aoff0 + k0, Asl + c0 * 8); glds16(Al + aoff1 + k0, Asl + c1 * 8);
    glds16(Bh + boff0 + k0, Bsh + c0 * 8);
    glds16(Bl + boff0 + k0, Bsl + c0 * 8);
    __syncthreads();
    f16x8 afh[4], afl[4], bfh[2], bfl[2];
#pragma unroll
    for (int i = 0; i < 4; i++) {
      const int ro = (wr * 64 + i * 16 + lc) * 32 + lr * 8;
      afh[i] = *(const f16x8*)(Ash + ro);
      afl[i] = *(const f16x8*)(Asl + ro);
    }
#pragma unroll
    for (int j = 0; j < 2; j++) {
      const int ro = (wc * 32 + j * 16 + lc) * 32 + lr * 8;
      bfh[j] = *(const f16x8*)(Bsh + ro);
      bfl[j] = *(const f16x8*)(Bsl + ro);
    }
#pragma unroll
    for (int i = 0; i < 4; i++)
#pragma unroll
      for (int j = 0; j < 2; j++) {
        acc[i][j] = __builtin_amdgcn_mfma_f32_16x16x32_f16(afh[i], bfh[j], acc[i][j], 0, 0, 0);
        acc[i][j] = __builtin_amdgcn_mfma_f32_16x16x32_f16(afh[i], bfl[j], acc[i][j], 0, 0, 0);
        acc[i][j] = __builtin_amdgcn_mfma_f32_16x16x32_f16(afl[i], bfh[j], acc[i][j], 0, 0, 0);
      }
    __syncthreads();
  }

#pragma unroll
  for (int i = 0; i < 4; i++)
#pragma unroll
    for (int j = 0; j < 2; j++) {
      const size_t rbase = row0 + wr * 64 + i * 16 + lr * 4;
      const size_t col = col0 + wc * 32 + j * 16 + lc;
#pragma unroll
      for (int r = 0; r < 4; r++) {
        size_t idx = (rbase + r) * N + col;
        outp[idx] = acc[i][j][r] + addsrc[idx];
      }
    }
}

// ---------------- MoE GEMM: gathered A rows via perm, per-expert B -----------
// DIVROW=1: A row = sid>>1 (token) ; DIVROW=0: A row = sid (slot)
template <int DIVROW, int BN>
__global__ __launch_bounds__(256) void gemm_moe_kernel(
    const f16* __restrict__ A, const f16* __restrict__ Ball, f16* __restrict__ outp,
    const int* __restrict__ perm, const int* __restrict__ counts,
    int N, int K, size_t strideB) {
  constexpr int JT = BN / 32;
  const int e = blockIdx.z;
  const int cnt = counts[e];
  const int bm = blockIdx.y;
  if (bm * 128 >= cnt) return;
  const f16* B = Ball + (size_t)e * strideB;
  __shared__ __attribute__((aligned(16))) f16 As[128 * 32];
  __shared__ __attribute__((aligned(16))) f16 Bs[BN * 32];
  const int tid = threadIdx.x;
  const size_t col0 = (size_t)blockIdx.x * BN;
  const int c0 = tid, c1 = tid + 256;
  const int pbase = e * 2048 + bm * 128;
  const int rt0 = c0 >> 2, rt1 = c1 >> 2;
  const int sid0 = (bm * 128 + rt0 < cnt) ? perm[pbase + rt0] : -1;
  const int sid1 = (bm * 128 + rt1 < cnt) ? perm[pbase + rt1] : -1;
  const size_t ar0 = DIVROW ? (size_t)(sid0 >> 1) : (size_t)sid0;
  const size_t ar1 = DIVROW ? (size_t)(sid1 >> 1) : (size_t)sid1;
  const f16* ap0 = A + ar0 * K + (c0 & 3) * 8;
  const f16* ap1 = A + ar1 * K + (c1 & 3) * 8;
  const f16* b0 = B + (col0 + (c0 >> 2)) * K + (c0 & 3) * 8;
  const f16* b1 = B + (col0 + ((BN == 128) ? (c1 >> 2) : 0)) * K + (c1 & 3) * 8;

  const int wave = tid >> 6, lane = tid & 63, lr = lane >> 4, lc = lane & 15;
  const int wr = wave >> 1, wc = wave & 1;

  f32x4 acc[4][JT];
#pragma unroll
  for (int i = 0; i < 4; i++)
#pragma unroll
    for (int j = 0; j < JT; j++) acc[i][j] = (f32x4){0.f, 0.f, 0.f, 0.f};

  for (int k0 = 0; k0 < K; k0 += 32) {
    glds16(b0 + k0, Bs + c0 * 8);
    if constexpr (BN == 128) glds16(b1 + k0, Bs + c1 * 8);
    f16x8 va0, va1;
#pragma unroll
    for (int x = 0; x < 8; x++) { va0[x] = (f16)0.f; va1[x] = (f16)0.f; }
    if (sid0 >= 0) va0 = *(const f16x8*)(ap0 + k0);
    if (sid1 >= 0) va1 = *(const f16x8*)(ap1 + k0);
    *(f16x8*)(As + c0 * 8) = va0;
    *(f16x8*)(As + c1 * 8) = va1;
    __syncthreads();
    f16x8 af[4], bfr[JT];
#pragma unroll
    for (int i = 0; i < 4; i++)
      af[i] = *(const f16x8*)(As + (wr * 64 + i * 16 + lc) * 32 + lr * 8);
#pragma unroll
    for (int j = 0; j < JT; j++)
      bfr[j] = *(const f16x8*)(Bs + (wc * (BN / 2) + j * 16 + lc) * 32 + lr * 8);
#pragma unroll
    for (int i = 0; i < 4; i++)
#pragma unroll
      for (int j = 0; j < JT; j++)
        acc[i][j] = __builtin_amdgcn_mfma_f32_16x16x32_f16(af[i], bfr[j], acc[i][j], 0, 0, 0);
    __syncthreads();
  }

  int sids[4][4];
#pragma unroll
  for (int i = 0; i < 4; i++)
#pragma unroll
    for (int r = 0; r < 4; r++) {
      int rit = wr * 64 + i * 16 + lr * 4 + r;
      sids[i][r] = (bm * 128 + rit < cnt) ? perm[pbase + rit] : -1;
    }
#pragma unroll
  for (int i = 0; i < 4; i++)
#pragma unroll
    for (int j = 0; j < JT; j++) {
      const size_t col = col0 + wc * (BN / 2) + j * 16 + lc;
#pragma unroll
      for (int r = 0; r < 4; r++)
        if (sids[i][r] >= 0)
          outp[(size_t)sids[i][r] * N + col] = (f16)acc[i][j][r];
    }
}

// ---------------- RoPE (fp64 phases), q scaled by HD^-0.5 * log2(e) ---------
__global__ void rope_kernel(const float* __restrict__ qkv, const int* __restrict__ pos,
                            f16* __restrict__ qr, f16* __restrict__ kr) {
  const int t = blockIdx.y;
  const int u = blockIdx.x * 256 + threadIdx.x;  // 0..767, use 0..639
  if (u >= 640) return;
  const float* base = qkv + (size_t)t * 1536;
  const int head = u >> 5, i = u & 31;
  const bool isq = head < 16;
  const int off = isq ? head * 64 + i : 1024 + (head - 16) * 64 + i;
  const float x1 = base[off], x2 = base[off + 32];
  const double ph = (double)pos[t] * exp((double)i * -0.28782313662425575);  // ln(1e4)/32
  const float c = (float)cos(ph), s = (float)sin(ph);
  const float r1 = x1 * c - x2 * s, r2 = x2 * c + x1 * s;
  if (isq) {
    // 0.125 * log2(e): base-2 softmax in attn
    const float qs = 0.18033688011116042f;
    qr[(size_t)t * 1024 + head * 64 + i] = (f16)(qs * r1);
    qr[(size_t)t * 1024 + head * 64 + i + 32] = (f16)(qs * r2);
  } else {
    const int kh = head - 16;
    kr[(size_t)t * 256 + kh * 64 + i] = (f16)r1;
    kr[(size_t)t * 256 + kh * 64 + i + 32] = (f16)r2;
  }
}

// ---------------- V transpose: qkvf[t][1280+kv*64+d] -> vt[kv*64+d][t] ------
__global__ void vtrans_kernel(const float* __restrict__ qkvf, f16* __restrict__ vt) {
  __shared__ float Ts[64 * 69];
  const int t0 = blockIdx.x * 64;
  const int kv = blockIdx.y;
  const int tid = threadIdx.x;
  const int tr = tid >> 2, jj = tid & 3;
  const float* src = qkvf + (size_t)(t0 + tr) * 1536 + 1280 + kv * 64 + jj * 16;
#pragma unroll
  for (int x = 0; x < 4; x++) {
    float4 f = *(const float4*)(src + x * 4);
    Ts[tr * 69 + jj * 16 + x * 4 + 0] = f.x;
    Ts[tr * 69 + jj * 16 + x * 4 + 1] = f.y;
    Ts[tr * 69 + jj * 16 + x * 4 + 2] = f.z;
    Ts[tr * 69 + jj * 16 + x * 4 + 3] = f.w;
  }
  __syncthreads();
  f16* dst = vt + (size_t)(kv * 64 + tr) * 2048 + t0 + jj * 16;
#pragma unroll
  for (int x = 0; x < 2; x++) {
    f16x8 o;
#pragma unroll
    for (int i = 0; i < 8; i++) o[i] = (f16)Ts[(jj * 16 + x * 8 + i) * 69 + tr];
    *(f16x8*)(dst + x * 8) = o;
  }
}

// ---------------- flash attention v3: S^T = K*Q^T formulation ---------------
// One wave per block, 16 q-rows, 256-wide K chunks. Softmax reductions are
// in-lane over S^T registers (+2 shuffles). No barriers anywhere.
__global__ __launch_bounds__(64, 3) void attn_kernel(
    const f16* __restrict__ qr, const f16* __restrict__ kr, const f16* __restrict__ vt,
    f16* __restrict__ ahi, f16* __restrict__ alo) {
  const int qt = 127 - (int)blockIdx.x;  // heavy tiles first
  const int h = blockIdx.y;
  const int kvh = h >> 2;
  __shared__ __attribute__((aligned(16))) f16 Pl[16 * 264];  // [t=16][s=256+8pad]
  const int lane = threadIdx.x;
  const int lr = lane >> 4, lc = lane & 15;
  const int trow = qt * 16 + lc;  // this lane's q row (S^T column)

  // Q as B-operand: B[n=lc=t][k=d]
  const f16* qp = qr + (size_t)trow * 1024 + h * 64 + lr * 8;
  f16x8 qf0 = *(const f16x8*)(qp);
  f16x8 qf1 = *(const f16x8*)(qp + 32);

  float m_run = -3e38f, l_run = 0.f;
  f32x4 accO[4];
#pragma unroll
  for (int jo = 0; jo < 4; jo++) accO[jo] = (f32x4){0.f, 0.f, 0.f, 0.f};

  const int nch = (qt >> 4) + 1;
  const f16* kbase = kr + kvh * 64 + lr * 8;
  const f16* vbase = vt + (size_t)(kvh * 64) * 2048 + lr * 8;

  for (int ch = 0; ch < nch; ++ch) {
    const int c0 = ch * 256;
    const bool last = (ch == nch - 1);

    // ---- S^T tiles: A = K rows (global gather), B = Q frag ----
    f32x4 st[16];
#pragma unroll
    for (int j = 0; j < 16; j++) {
      const f16* kp = kbase + (size_t)(c0 + j * 16 + lc) * 256;
      f16x8 ka0 = *(const f16x8*)(kp);
      f16x8 ka1 = *(const f16x8*)(kp + 32);
      f32x4 s = (f32x4){0.f, 0.f, 0.f, 0.f};
      s = __builtin_amdgcn_mfma_f32_16x16x32_f16(ka0, qf0, s, 0, 0, 0);
      s = __builtin_amdgcn_mfma_f32_16x16x32_f16(ka1, qf1, s, 0, 0, 0);
      st[j] = s;
    }

    // ---- causal mask (only the last chunk can cross the diagonal) ----
    if (last) {
#pragma unroll
      for (int j = 0; j < 16; j++)
#pragma unroll
        for (int r = 0; r < 4; r++)
          if (c0 + j * 16 + lr * 4 + r > trow) st[j][r] = -3e38f;
    }

    // ---- chunk max: in-lane over 64 regs, then 2 shuffles across lr ----
    float mc = -3e38f;
#pragma unroll
    for (int j = 0; j < 16; j++) {
      mc = fmaxf(mc, fmaxf(fmaxf(st[j][0], st[j][1]), fmaxf(st[j][2], st[j][3])));
    }
    mc = fmaxf(mc, __shfl_xor(mc, 16));
    mc = fmaxf(mc, __shfl_xor(mc, 32));
    const float mn = fmaxf(m_run, mc);
    const float alpha = __builtin_amdgcn_exp2f(m_run - mn);
    m_run = mn;

    // ---- exp2, packed P^T stores, in-lane sum ----
    float ls = 0.f;
#pragma unroll
    for (int j = 0; j < 16; j++) {
      f16x4 pv;
#pragma unroll
      for (int r = 0; r < 4; r++) {
        float e = __builtin_amdgcn_exp2f(st[j][r] - mn);
        ls += e;
        pv[r] = (f16)e;
      }
      *(f16x4*)(Pl + lc * 264 + j * 16 + lr * 4) = pv;  // P^T[t=lc][s=16j+4lr+r]
    }
    ls += __shfl_xor(ls, 16);
    ls += __shfl_xor(ls, 32);
    l_run = l_run * alpha + ls;
#pragma unroll
    for (int jo = 0; jo < 4; jo++) accO[jo] *= alpha;

    // ---- O^T += V^T * P^T : A = V^T frags (global), B = P^T from LDS ----
#pragma unroll
    for (int kkt = 0; kkt < 8; kkt++) {
      f16x8 pb = *(const f16x8*)(Pl + lc * 264 + kkt * 32 + lr * 8);
#pragma unroll
      for (int jo = 0; jo < 4; jo++) {
        f16x8 va = *(const f16x8*)(vbase + (size_t)(jo * 16 + lc) * 2048 + c0 + kkt * 32);
        accO[jo] = __builtin_amdgcn_mfma_f32_16x16x32_f16(va, pb, accO[jo], 0, 0, 0);
      }
    }
  }

  // ---- epilogue: O^T lane holds col t=lc, rows d = jo*16+lr*4+r ----
  const float inv = 1.f / l_run;
#pragma unroll
  for (int jo = 0; jo < 4; jo++) {
    f16x4 hi4, lo4;
#pragma unroll
    for (int r = 0; r < 4; r++) {
      float o = accO[jo][r] * inv;
      f16 hv = (f16)o;
      hi4[r] = hv;
      lo4[r] = (f16)(o - (float)hv);
    }
    const size_t idx = (size_t)trow * 1024 + h * 64 + jo * 16 + lr * 4;
    *(f16x4*)(ahi + idx) = hi4;
    *(f16x4*)(alo + idx) = lo4;
  }
}

// ---------------- routing: fp32 norm + gate + top2, compaction --------------
__global__ void routing_kernel(const float* __restrict__ resA,
                               const float* __restrict__ postw,
                               const float* __restrict__ gw,
                               int* __restrict__ counts, int* __restrict__ perm,
                               float* __restrict__ rw) {
  const int t = blockIdx.x * 4 + (threadIdx.x >> 6);
  const int lane = threadIdx.x & 63;
  const float* x = resA + (size_t)t * 1024;
  float v[16]; float ss = 0.f;
#pragma unroll
  for (int j = 0; j < 16; j++) { float a = x[lane + 64 * j]; v[j] = a; ss += a * a; }
#pragma unroll
  for (int m = 1; m < 64; m <<= 1) ss += __shfl_xor(ss, m);
  const float rs = rsqrtf(ss * (1.f / 1024.f) + 1e-5f);
#pragma unroll
  for (int j = 0; j < 16; j++) v[j] *= rs * postw[lane + 64 * j];
  float lg[8];
#pragma unroll
  for (int e = 0; e < 8; e++) {
    float p = 0.f;
    const float* g = gw + (size_t)e * 1024;
#pragma unroll
    for (int j = 0; j < 16; j++) p += v[j] * g[lane + 64 * j];
#pragma unroll
    for (int m = 1; m < 64; m <<= 1) p += __shfl_xor(p, m);
    lg[e] = p;
  }
  if (lane == 0) {
    int e0 = 0; float b0 = lg[0];
#pragma unroll
    for (int e = 1; e < 8; e++) if (lg[e] > b0) { b0 = lg[e]; e0 = e; }
    int e1 = -1; float b1 = -3e38f;
#pragma unroll
    for (int e = 0; e < 8; e++) if (e != e0 && lg[e] > b1) { b1 = lg[e]; e1 = e; }
    const float w0 = 1.f / (1.f + expf(b1 - b0));  // p0/(p0+p1)
    const float w1 = 1.f - w0;
    int p0 = atomicAdd(&counts[e0], 1);
    perm[e0 * 2048 + p0] = t * 2;
    int p1 = atomicAdd(&counts[e1], 1);
    perm[e1 * 2048 + p1] = t * 2 + 1;
    rw[t * 2] = w0;
    rw[t * 2 + 1] = w1;
  }
}

// ---------------- silu(g)*u ----------------
__global__ void silu_mul_kernel(const f16* __restrict__ gu, f16* __restrict__ outp, int lgN) {
  const int N = 1 << lgN;
  const size_t i4 = ((size_t)blockIdx.x * 256 + threadIdx.x) * 4;
  const size_t r = i4 >> lgN;
  const int c = (int)(i4 & (N - 1));
  const f16* gp = gu + r * (size_t)(2 * N) + c;
  f16x4 g = *(const f16x4*)gp;
  f16x4 u = *(const f16x4*)(gp + N);
  f16x4 o;
#pragma unroll
  for (int x = 0; x < 4; x++) {
    float gg = (float)g[x], uu = (float)u[x];
    o[x] = (f16)(gg / (1.f + __expf(-gg)) * uu);
  }
  *(f16x4*)(outp + r * (size_t)N + c) = o;
}

// ---------------- final: out += w0*eo[2t] + w1*eo[2t+1] ----------------
__global__ void final_add_kernel(float* __restrict__ outp, const f16* __restrict__ eo,
                                 const float* __restrict__ rw) {
  const size_t i4 = ((size_t)blockIdx.x * 256 + threadIdx.x) * 4;
  const int t = (int)(i4 >> 10);
  const int c = (int)(i4 & 1023);
  const float w0 = rw[2 * t], w1 = rw[2 * t + 1];
  f16x4 a = *(const f16x4*)(eo + ((size_t)(2 * t)) * 1024 + c);
  f16x4 b = *(const f16x4*)(eo + ((size_t)(2 * t + 1)) * 1024 + c);
  float4 o = *(float4*)(outp + i4);
  o.x += w0 * (float)a[0] + w1 * (float)b[0];
  o.y += w0 * (float)a[1] + w1 * (float)b[1];
  o.z += w0 * (float)a[2] + w1 * (float)b[2];
  o.w += w0 * (float)a[3] + w1 * (float)b[3];
  *(float4*)(outp + i4) = o;
}

extern "C" void kernel_launch(void* const* d_in, const int* in_sizes, int n_in,
                              void* d_out, int out_size, void* d_ws, size_t ws_size,
                              hipStream_t stream) {
  const int* positions = (const int*)d_in[0];
  const float* hidden = (const float*)d_in[1];
  const float* in_ln = (const float*)d_in[2];
  const float* post_ln = (const float*)d_in[3];
  const float* res_ln = (const float*)d_in[4];
  const float* qkv_w = (const float*)d_in[5];
  const float* o_w = (const float*)d_in[6];
  const float* gate_w = (const float*)d_in[7];
  const float* ws_w = (const float*)d_in[8];
  const float* w2s_w = (const float*)d_in[9];
  const float* w13_w = (const float*)d_in[10];
  const float* w2_w = (const float*)d_in[11];
  float* out = (float*)d_out;

  char* p = (char*)d_ws;
  auto alloc = [&](size_t b) { void* r = (void*)p; p += (b + 255) & ~(size_t)255; return r; };

  f16* wqkv = (f16*)alloc((size_t)1536 * 1024 * 2);
  f16* woh  = (f16*)alloc((size_t)1024 * 1024 * 2);
  f16* wol  = (f16*)alloc((size_t)1024 * 1024 * 2);
  f16* wws  = (f16*)alloc((size_t)8 * 4096 * 1024 * 2);
  f16* ww2  = (f16*)alloc((size_t)8 * 1024 * 2048 * 2);
  f16* w13  = (f16*)alloc((size_t)2048 * 1024 * 2);
  f16* w2c  = (f16*)alloc((size_t)1024 * 1024 * 2);
  f16* hn   = (f16*)alloc((size_t)2048 * 1024 * 2);
  float* qkvf = (float*)alloc((size_t)2048 * 1536 * 4);
  f16* qr = (f16*)alloc((size_t)2048 * 1024 * 2);
  f16* kr = (f16*)alloc((size_t)2048 * 256 * 2);
  f16* vt = (f16*)alloc((size_t)256 * 2048 * 2);
  f16* ath = (f16*)alloc((size_t)2048 * 1024 * 2);
  f16* atl = (f16*)alloc((size_t)2048 * 1024 * 2);
  float* resA = (float*)alloc((size_t)2048 * 1024 * 4);
  f16* rn = (f16*)alloc((size_t)2048 * 1024 * 2);
  f16* mn = (f16*)alloc((size_t)2048 * 1024 * 2);
  f16* gu13 = (f16*)alloc((size_t)2048 * 2048 * 2);
  f16* act13 = (f16*)alloc((size_t)2048 * 1024 * 2);
  f16* gum = (f16*)alloc((size_t)4096 * 4096 * 2);
  f16* actm = (f16*)alloc((size_t)4096 * 2048 * 2);
  f16* eo = (f16*)alloc((size_t)4096 * 1024 * 2);
  float* rw = (float*)alloc((size_t)4096 * 4);
  int* counts = (int*)alloc(256);
  int* perm = (int*)alloc((size_t)8 * 2048 * 4);

  // weight conversions (ws is re-poisoned before every timed launch)
  cvt_f16_kernel<<<dim3(1536 * 1024 / 1024), dim3(256), 0, stream>>>(qkv_w, wqkv);
  cvt_f16_kernel<<<dim3(8 * 4096 * 1024 / 1024), dim3(256), 0, stream>>>(ws_w, wws);
  cvt_f16_kernel<<<dim3(8 * 1024 * 2048 / 1024), dim3(256), 0, stream>>>(w2s_w, ww2);
  cvt_f16_kernel<<<dim3(2048 * 1024 / 1024), dim3(256), 0, stream>>>(w13_w, w13);
  cvt_f16_kernel<<<dim3(1024 * 1024 / 1024), dim3(256), 0, stream>>>(w2_w, w2c);
  cvt_f16x2_kernel<<<dim3(1024 * 1024 / 1024), dim3(256), 0, stream>>>(o_w, woh, wol);
  hipMemsetAsync(counts, 0, 256, stream);

  // attention path
  rmsnorm_kernel<<<dim3(512), dim3(256), 0, stream>>>(hidden, in_ln, hn);
  gemm_f16_kernel<0, 64><<<dim3(24, 16), dim3(256), 0, stream>>>(
      hn, wqkv, (void*)qkvf, (const float*)nullptr, 2048, 1536, 1024);
  rope_kernel<<<dim3(3, 2048), dim3(256), 0, stream>>>(qkvf, positions, qr, kr);
  vtrans_kernel<<<dim3(32, 4), dim3(256), 0, stream>>>(qkvf, vt);
  attn_kernel<<<dim3(128, 16), dim3(64), 0, stream>>>(qr, kr, vt, ath, atl);
  gemm_f16x2_add_kernel<<<dim3(16, 16), dim3(256), 0, stream>>>(
      ath, atl, woh, wol, resA, hidden, 2048, 1024, 1024);

  // norms + routing off residual_attn
  rmsnorm_dual_kernel<<<dim3(512), dim3(256), 0, stream>>>(resA, res_ln, post_ln, rn, mn);
  routing_kernel<<<dim3(512), dim3(256), 0, stream>>>(resA, post_ln, gate_w, counts, perm, rw);

  // residual MLP -> d_out holds residual_mlp
  gemm_f16_kernel<2, 64><<<dim3(32, 16), dim3(256), 0, stream>>>(
      rn, w13, (void*)gu13, (const float*)nullptr, 2048, 2048, 1024);
  silu_mul_kernel<<<dim3(2048 * 1024 / 1024), dim3(256), 0, stream>>>(gu13, act13, 10);
  gemm_f16_kernel<1, 64><<<dim3(16, 16), dim3(256), 0, stream>>>(
      act13, w2c, (void*)out, resA, 2048, 1024, 1024);

  // MoE (top-2 sparse)
  gemm_moe_kernel<1, 128><<<dim3(32, 16, 8), dim3(256), 0, stream>>>(
      mn, wws, gum, perm, counts, 4096, 1024, (size_t)4096 * 1024);
  silu_mul_kernel<<<dim3(4096 * 2048 / 1024), dim3(256), 0, stream>>>(gum, actm, 11);
  gemm_moe_kernel<0, 64><<<dim3(16, 16, 8), dim3(256), 0, stream>>>(
      actm, ww2, eo, perm, counts, 1024, 2048, (size_t)1024 * 2048);
  final_add_kernel<<<dim3(2048 * 1024 / 1024), dim3(256), 0, stream>>>(out, eo, rw);
}

// Round 4
// 667.983 us; speedup vs baseline: 1.1742x; 1.1489x over previous
//
#include <hip/hip_runtime.h>
#include <stdint.h>

// ArcticDecoderLayer on MI355X (gfx950).
// Precision plan: f16 MFMA everywhere except (a) o-proj GEMM in f16 hi/lo split
// (3 MFMAs) because its error feeds MoE top-k routing, (b) routing itself in
// fp32, (c) RoPE phases in fp64 (matches numpy's float64 promotion).
// R4: attention keeps the S^T = K*Q^T formulation (in-lane softmax) but adds
// 4-wave blocks (64 q-rows) with K/V^T staged in PADDED LDS (stride 72/136
// f16 -> conflict-free b128 access; R1's unpadded strides were 16-way).
// Global K/V traffic drops ~45x (6.3 GB L2 -> 140 MB). 52 KB LDS -> 3 blk/CU.
// T=2048 H=1024 NH=16 NKV=4 HD=64 I=2048 E=8 TOPK=2

typedef _Float16 f16;
typedef _Float16 f16x8 __attribute__((ext_vector_type(8)));
typedef _Float16 f16x4 __attribute__((ext_vector_type(4)));
typedef float f32x4 __attribute__((ext_vector_type(4)));

#define DEV __device__ __forceinline__

DEV void glds16(const void* g, void* l) {
  __builtin_amdgcn_global_load_lds((const __attribute__((address_space(1))) void*)g,
                                   (__attribute__((address_space(3))) void*)l, 16, 0, 0);
}

// ---------------- conversions ----------------
__global__ void cvt_f16_kernel(const float* __restrict__ in, f16* __restrict__ outp) {
  const size_t i = ((size_t)blockIdx.x * 256 + threadIdx.x) * 4;
  float4 f = *(const float4*)(in + i);
  f16x4 o;
  o[0] = (f16)f.x; o[1] = (f16)f.y; o[2] = (f16)f.z; o[3] = (f16)f.w;
  *(f16x4*)(outp + i) = o;
}

__global__ void cvt_f16x2_kernel(const float* __restrict__ in,
                                 f16* __restrict__ oh, f16* __restrict__ ol) {
  const size_t i = ((size_t)blockIdx.x * 256 + threadIdx.x) * 4;
  float4 f = *(const float4*)(in + i);
  f16x4 h, l;
  h[0] = (f16)f.x; l[0] = (f16)(f.x - (float)h[0]);
  h[1] = (f16)f.y; l[1] = (f16)(f.y - (float)h[1]);
  h[2] = (f16)f.z; l[2] = (f16)(f.z - (float)h[2]);
  h[3] = (f16)f.w; l[3] = (f16)(f.w - (float)h[3]);
  *(f16x4*)(oh + i) = h;
  *(f16x4*)(ol + i) = l;
}

// ---------------- RMS norms (wave per row, 1024 cols) ----------------
__global__ void rmsnorm_kernel(const float* __restrict__ in, const float* __restrict__ w,
                               f16* __restrict__ outp) {
  const int t = blockIdx.x * 4 + (threadIdx.x >> 6);
  const int lane = threadIdx.x & 63;
  const float* x = in + (size_t)t * 1024;
  float v[16]; float ss = 0.f;
#pragma unroll
  for (int j = 0; j < 16; j++) { float a = x[lane + 64 * j]; v[j] = a; ss += a * a; }
#pragma unroll
  for (int m = 1; m < 64; m <<= 1) ss += __shfl_xor(ss, m);
  const float rs = rsqrtf(ss * (1.f / 1024.f) + 1e-5f);
#pragma unroll
  for (int j = 0; j < 16; j++)
    outp[(size_t)t * 1024 + lane + 64 * j] = (f16)(v[j] * rs * w[lane + 64 * j]);
}

__global__ void rmsnorm_dual_kernel(const float* __restrict__ in,
                                    const float* __restrict__ w1, const float* __restrict__ w2,
                                    f16* __restrict__ o1, f16* __restrict__ o2) {
  const int t = blockIdx.x * 4 + (threadIdx.x >> 6);
  const int lane = threadIdx.x & 63;
  const float* x = in + (size_t)t * 1024;
  float v[16]; float ss = 0.f;
#pragma unroll
  for (int j = 0; j < 16; j++) { float a = x[lane + 64 * j]; v[j] = a; ss += a * a; }
#pragma unroll
  for (int m = 1; m < 64; m <<= 1) ss += __shfl_xor(ss, m);
  const float rs = rsqrtf(ss * (1.f / 1024.f) + 1e-5f);
#pragma unroll
  for (int j = 0; j < 16; j++) {
    float nv = v[j] * rs;
    size_t idx = (size_t)t * 1024 + lane + 64 * j;
    o1[idx] = (f16)(nv * w1[lane + 64 * j]);
    o2[idx] = (f16)(nv * w2[lane + 64 * j]);
  }
}

// ---------------- main GEMM: C[M,N] = A[M,K] * B[N,K]^T, 128xBN x32 tiles ----
// EPI: 0 = fp32 store, 1 = fp32 store + addsrc, 2 = f16 store
template <int EPI, int BN>
__global__ __launch_bounds__(256) void gemm_f16_kernel(
    const f16* __restrict__ A, const f16* __restrict__ B,
    void* __restrict__ outp, const float* __restrict__ addsrc,
    int M, int N, int K) {
  constexpr int JT = BN / 32;  // col fragments per wave (wave covers BN/2 cols)
  __shared__ __attribute__((aligned(16))) f16 As[128 * 32];
  __shared__ __attribute__((aligned(16))) f16 Bs[BN * 32];
  const int tid = threadIdx.x;
  const size_t row0 = (size_t)blockIdx.y * 128, col0 = (size_t)blockIdx.x * BN;
  const int c0 = tid, c1 = tid + 256;
  const f16* a0 = A + (row0 + (c0 >> 2)) * K + (c0 & 3) * 8;
  const f16* a1 = A + (row0 + (c1 >> 2)) * K + (c1 & 3) * 8;
  const f16* b0 = B + (col0 + (c0 >> 2)) * K + (c0 & 3) * 8;
  const f16* b1 = B + (col0 + ((BN == 128) ? (c1 >> 2) : 0)) * K + (c1 & 3) * 8;

  const int wave = tid >> 6, lane = tid & 63, lr = lane >> 4, lc = lane & 15;
  const int wr = wave >> 1, wc = wave & 1;

  f32x4 acc[4][JT];
#pragma unroll
  for (int i = 0; i < 4; i++)
#pragma unroll
    for (int j = 0; j < JT; j++) acc[i][j] = (f32x4){0.f, 0.f, 0.f, 0.f};

  for (int k0 = 0; k0 < K; k0 += 32) {
    glds16(a0 + k0, As + c0 * 8); glds16(a1 + k0, As + c1 * 8);
    glds16(b0 + k0, Bs + c0 * 8);
    if constexpr (BN == 128) glds16(b1 + k0, Bs + c1 * 8);
    __syncthreads();
    f16x8 af[4], bfr[JT];
#pragma unroll
    for (int i = 0; i < 4; i++)
      af[i] = *(const f16x8*)(As + (wr * 64 + i * 16 + lc) * 32 + lr * 8);
#pragma unroll
    for (int j = 0; j < JT; j++)
      bfr[j] = *(const f16x8*)(Bs + (wc * (BN / 2) + j * 16 + lc) * 32 + lr * 8);
#pragma unroll
    for (int i = 0; i < 4; i++)
#pragma unroll
      for (int j = 0; j < JT; j++)
        acc[i][j] = __builtin_amdgcn_mfma_f32_16x16x32_f16(af[i], bfr[j], acc[i][j], 0, 0, 0);
    __syncthreads();
  }

#pragma unroll
  for (int i = 0; i < 4; i++)
#pragma unroll
    for (int j = 0; j < JT; j++) {
      const size_t rbase = row0 + wr * 64 + i * 16 + lr * 4;
      const size_t col = col0 + wc * (BN / 2) + j * 16 + lc;
#pragma unroll
      for (int r = 0; r < 4; r++) {
        size_t idx = (rbase + r) * N + col;
        if constexpr (EPI == 0) ((float*)outp)[idx] = acc[i][j][r];
        else if constexpr (EPI == 1) ((float*)outp)[idx] = acc[i][j][r] + addsrc[idx];
        else ((f16*)outp)[idx] = (f16)acc[i][j][r];
      }
    }
}

// ---------------- o-proj GEMM, f16 hi/lo split (3 MFMAs), +residual, 128x64 -
__global__ __launch_bounds__(256) void gemm_f16x2_add_kernel(
    const f16* __restrict__ Ah, const f16* __restrict__ Al,
    const f16* __restrict__ Bh, const f16* __restrict__ Bl,
    float* __restrict__ outp, const float* __restrict__ addsrc,
    int M, int N, int K) {
  __shared__ __attribute__((aligned(16))) f16 Ash[128 * 32];
  __shared__ __attribute__((aligned(16))) f16 Asl[128 * 32];
  __shared__ __attribute__((aligned(16))) f16 Bsh[64 * 32];
  __shared__ __attribute__((aligned(16))) f16 Bsl[64 * 32];
  const int tid = threadIdx.x;
  const size_t row0 = (size_t)blockIdx.y * 128, col0 = (size_t)blockIdx.x * 64;
  const int c0 = tid, c1 = tid + 256;
  const size_t aoff0 = (row0 + (c0 >> 2)) * K + (c0 & 3) * 8;
  const size_t aoff1 = (row0 + (c1 >> 2)) * K + (c1 & 3) * 8;
  const size_t boff0 = (col0 + (c0 >> 2)) * K + (c0 & 3) * 8;

  const int wave = tid >> 6, lane = tid & 63, lr = lane >> 4, lc = lane & 15;
  const int wr = wave >> 1, wc = wave & 1;

  f32x4 acc[4][2];
#pragma unroll
  for (int i = 0; i < 4; i++)
#pragma unroll
    for (int j = 0; j < 2; j++) acc[i][j] = (f32x4){0.f, 0.f, 0.f, 0.f};

  for (int k0 = 0; k0 < K; k0 += 32) {
    glds16(Ah + aoff0 + k0, Ash + c0 * 8); glds16(Ah + aoff1 + k0, Ash + c1 * 8);
    glds16(Al + aoff0 + k0, Asl + c0 * 8); glds16(Al + aoff1 + k0, Asl + c1 * 8);
    glds16(Bh + boff0 + k0, Bsh + c0 * 8);
    glds16(Bl + boff0 + k0, Bsl + c0 * 8);
    __syncthreads();
    f16x8 afh[4], afl[4], bfh[2], bfl[2];
#pragma unroll
    for (int i = 0; i < 4; i++) {
      const int ro = (wr * 64 + i * 16 + lc) * 32 + lr * 8;
      afh[i] = *(const f16x8*)(Ash + ro);
      afl[i] = *(const f16x8*)(Asl + ro);
    }
#pragma unroll
    for (int j = 0; j < 2; j++) {
      const int ro = (wc * 32 + j * 16 + lc) * 32 + lr * 8;
      bfh[j] = *(const f16x8*)(Bsh + ro);
      bfl[j] = *(const f16x8*)(Bsl + ro);
    }
#pragma unroll
    for (int i = 0; i < 4; i++)
#pragma unroll
      for (int j = 0; j < 2; j++) {
        acc[i][j] = __builtin_amdgcn_mfma_f32_16x16x32_f16(afh[i], bfh[j], acc[i][j], 0, 0, 0);
        acc[i][j] = __builtin_amdgcn_mfma_f32_16x16x32_f16(afh[i], bfl[j], acc[i][j], 0, 0, 0);
        acc[i][j] = __builtin_amdgcn_mfma_f32_16x16x32_f16(afl[i], bfh[j], acc[i][j], 0, 0, 0);
      }
    __syncthreads();
  }

#pragma unroll
  for (int i = 0; i < 4; i++)
#pragma unroll
    for (int j = 0; j < 2; j++) {
      const size_t rbase = row0 + wr * 64 + i * 16 + lr * 4;
      const size_t col = col0 + wc * 32 + j * 16 + lc;
#pragma unroll
      for (int r = 0; r < 4; r++) {
        size_t idx = (rbase + r) * N + col;
        outp[idx] = acc[i][j][r] + addsrc[idx];
      }
    }
}

// ---------------- MoE GEMM: gathered A rows via perm, per-expert B -----------
// DIVROW=1: A row = sid>>1 (token) ; DIVROW=0: A row = sid (slot)
template <int DIVROW, int BN>
__global__ __launch_bounds__(256) void gemm_moe_kernel(
    const f16* __restrict__ A, const f16* __restrict__ Ball, f16* __restrict__ outp,
    const int* __restrict__ perm, const int* __restrict__ counts,
    int N, int K, size_t strideB) {
  constexpr int JT = BN / 32;
  const int e = blockIdx.z;
  const int cnt = counts[e];
  const int bm = blockIdx.y;
  if (bm * 128 >= cnt) return;
  const f16* B = Ball + (size_t)e * strideB;
  __shared__ __attribute__((aligned(16))) f16 As[128 * 32];
  __shared__ __attribute__((aligned(16))) f16 Bs[BN * 32];
  const int tid = threadIdx.x;
  const size_t col0 = (size_t)blockIdx.x * BN;
  const int c0 = tid, c1 = tid + 256;
  const int pbase = e * 2048 + bm * 128;
  const int rt0 = c0 >> 2, rt1 = c1 >> 2;
  const int sid0 = (bm * 128 + rt0 < cnt) ? perm[pbase + rt0] : -1;
  const int sid1 = (bm * 128 + rt1 < cnt) ? perm[pbase + rt1] : -1;
  const size_t ar0 = DIVROW ? (size_t)(sid0 >> 1) : (size_t)sid0;
  const size_t ar1 = DIVROW ? (size_t)(sid1 >> 1) : (size_t)sid1;
  const f16* ap0 = A + ar0 * K + (c0 & 3) * 8;
  const f16* ap1 = A + ar1 * K + (c1 & 3) * 8;
  const f16* b0 = B + (col0 + (c0 >> 2)) * K + (c0 & 3) * 8;
  const f16* b1 = B + (col0 + ((BN == 128) ? (c1 >> 2) : 0)) * K + (c1 & 3) * 8;

  const int wave = tid >> 6, lane = tid & 63, lr = lane >> 4, lc = lane & 15;
  const int wr = wave >> 1, wc = wave & 1;

  f32x4 acc[4][JT];
#pragma unroll
  for (int i = 0; i < 4; i++)
#pragma unroll
    for (int j = 0; j < JT; j++) acc[i][j] = (f32x4){0.f, 0.f, 0.f, 0.f};

  for (int k0 = 0; k0 < K; k0 += 32) {
    glds16(b0 + k0, Bs + c0 * 8);
    if constexpr (BN == 128) glds16(b1 + k0, Bs + c1 * 8);
    f16x8 va0, va1;
#pragma unroll
    for (int x = 0; x < 8; x++) { va0[x] = (f16)0.f; va1[x] = (f16)0.f; }
    if (sid0 >= 0) va0 = *(const f16x8*)(ap0 + k0);
    if (sid1 >= 0) va1 = *(const f16x8*)(ap1 + k0);
    *(f16x8*)(As + c0 * 8) = va0;
    *(f16x8*)(As + c1 * 8) = va1;
    __syncthreads();
    f16x8 af[4], bfr[JT];
#pragma unroll
    for (int i = 0; i < 4; i++)
      af[i] = *(const f16x8*)(As + (wr * 64 + i * 16 + lc) * 32 + lr * 8);
#pragma unroll
    for (int j = 0; j < JT; j++)
      bfr[j] = *(const f16x8*)(Bs + (wc * (BN / 2) + j * 16 + lc) * 32 + lr * 8);
#pragma unroll
    for (int i = 0; i < 4; i++)
#pragma unroll
      for (int j = 0; j < JT; j++)
        acc[i][j] = __builtin_amdgcn_mfma_f32_16x16x32_f16(af[i], bfr[j], acc[i][j], 0, 0, 0);
    __syncthreads();
  }

  int sids[4][4];
#pragma unroll
  for (int i = 0; i < 4; i++)
#pragma unroll
    for (int r = 0; r < 4; r++) {
      int rit = wr * 64 + i * 16 + lr * 4 + r;
      sids[i][r] = (bm * 128 + rit < cnt) ? perm[pbase + rit] : -1;
    }
#pragma unroll
  for (int i = 0; i < 4; i++)
#pragma unroll
    for (int j = 0; j < JT; j++) {
      const size_t col = col0 + wc * (BN / 2) + j * 16 + lc;
#pragma unroll
      for (int r = 0; r < 4; r++)
        if (sids[i][r] >= 0)
          outp[(size_t)sids[i][r] * N + col] = (f16)acc[i][j][r];
    }
}

// ---------------- RoPE (fp64 phases), q scaled by HD^-0.5 * log2(e) ---------
__global__ void rope_kernel(const float* __restrict__ qkv, const int* __restrict__ pos,
                            f16* __restrict__ qr, f16* __restrict__ kr) {
  const int t = blockIdx.y;
  const int u = blockIdx.x * 256 + threadIdx.x;  // 0..767, use 0..639
  if (u >= 640) return;
  const float* base = qkv + (size_t)t * 1536;
  const int head = u >> 5, i = u & 31;
  const bool isq = head < 16;
  const int off = isq ? head * 64 + i : 1024 + (head - 16) * 64 + i;
  const float x1 = base[off], x2 = base[off + 32];
  const double ph = (double)pos[t] * exp((double)i * -0.28782313662425575);  // ln(1e4)/32
  const float c = (float)cos(ph), s = (float)sin(ph);
  const float r1 = x1 * c - x2 * s, r2 = x2 * c + x1 * s;
  if (isq) {
    // 0.125 * log2(e): base-2 softmax in attn
    const float qs = 0.18033688011116042f;
    qr[(size_t)t * 1024 + head * 64 + i] = (f16)(qs * r1);
    qr[(size_t)t * 1024 + head * 64 + i + 32] = (f16)(qs * r2);
  } else {
    const int kh = head - 16;
    kr[(size_t)t * 256 + kh * 64 + i] = (f16)r1;
    kr[(size_t)t * 256 + kh * 64 + i + 32] = (f16)r2;
  }
}

// ---------------- V transpose: qkvf[t][1280+kv*64+d] -> vt[kv*64+d][t] ------
__global__ void vtrans_kernel(const float* __restrict__ qkvf, f16* __restrict__ vt) {
  __shared__ float Ts[64 * 69];
  const int t0 = blockIdx.x * 64;
  const int kv = blockIdx.y;
  const int tid = threadIdx.x;
  const int tr = tid >> 2, jj = tid & 3;
  const float* src = qkvf + (size_t)(t0 + tr) * 1536 + 1280 + kv * 64 + jj * 16;
#pragma unroll
  for (int x = 0; x < 4; x++) {
    float4 f = *(const float4*)(src + x * 4);
    Ts[tr * 69 + jj * 16 + x * 4 + 0] = f.x;
    Ts[tr * 69 + jj * 16 + x * 4 + 1] = f.y;
    Ts[tr * 69 + jj * 16 + x * 4 + 2] = f.z;
    Ts[tr * 69 + jj * 16 + x * 4 + 3] = f.w;
  }
  __syncthreads();
  f16* dst = vt + (size_t)(kv * 64 + tr) * 2048 + t0 + jj * 16;
#pragma unroll
  for (int x = 0; x < 2; x++) {
    f16x8 o;
#pragma unroll
    for (int i = 0; i < 8; i++) o[i] = (f16)Ts[(jj * 16 + x * 8 + i) * 69 + tr];
    *(f16x8*)(dst + x * 8) = o;
  }
}

// ---------------- flash attention v4: S^T = K*Q^T + LDS-staged K/V ----------
// 4 waves/block, each wave 16 q-rows (block = 64). K,V^T staged per 128-chunk
// into padded LDS (stride 72 / 136 f16 -> conflict-free b128). Next-chunk
// global loads prefetched into VGPRs during compute. 52 KB LDS -> 3 blk/CU.
__global__ __launch_bounds__(256, 3) void attn_kernel(
    const f16* __restrict__ qr, const f16* __restrict__ kr, const f16* __restrict__ vt,
    f16* __restrict__ ahi, f16* __restrict__ alo) {
  const int qt = 31 - (int)blockIdx.x;  // 64-row q tiles, heavy first
  const int h = blockIdx.y;
  const int kvh = h >> 2;
  __shared__ __attribute__((aligned(16))) f16 Ks[128 * 72];   // [k=128][d=64 +8pad]
  __shared__ __attribute__((aligned(16))) f16 Vs[64 * 136];   // [d=64][k=128 +8pad]
  __shared__ __attribute__((aligned(16))) f16 Pl[4 * 16 * 136];  // per-wave P^T strips
  const int tid = threadIdx.x;
  const int wave = tid >> 6, lane = tid & 63, lr = lane >> 4, lc = lane & 15;
  const int trow = qt * 64 + wave * 16 + lc;  // this lane's q row (S^T column)
  f16* Pw = Pl + wave * 16 * 136;

  // staging roles (whole block)
  const int krow = tid >> 3, kcol = (tid & 7) * 8;    // 32 k-rows per iter, 4 iters
  const int vrow = tid >> 4, vcol = (tid & 15) * 8;   // 16 d-rows per iter, 4 iters
  const f16* kgbase = kr + (size_t)kvh * 64 + kcol;
  const f16* vgbase = vt + (size_t)(kvh * 64 + vrow) * 2048 + vcol;

  // Q as B-operand: B[n=lc=t][k=d]
  const f16* qp = qr + (size_t)trow * 1024 + h * 64 + lr * 8;
  f16x8 qf0 = *(const f16x8*)(qp);
  f16x8 qf1 = *(const f16x8*)(qp + 32);

  float m_run = -3e38f, l_run = 0.f;
  f32x4 accO[4];
#pragma unroll
  for (int jo = 0; jo < 4; jo++) accO[jo] = (f32x4){0.f, 0.f, 0.f, 0.f};

  const int nch = (qt >> 1) + 1;  // 128-wide chunks

  f16x8 kreg[4], vreg[4];
  // preload chunk 0
#pragma unroll
  for (int it = 0; it < 4; it++) {
    kreg[it] = *(const f16x8*)(kgbase + (size_t)(it * 32 + krow) * 256);
    vreg[it] = *(const f16x8*)(vgbase + it * 16 * 2048);
  }

  for (int ch = 0; ch < nch; ++ch) {
    const int c0 = ch * 128;
    const bool last = (ch == nch - 1);

    __syncthreads();  // previous chunk's LDS reads complete
#pragma unroll
    for (int it = 0; it < 4; it++) {
      *(f16x8*)(Ks + (it * 32 + krow) * 72 + kcol) = kreg[it];
      *(f16x8*)(Vs + (it * 16 + vrow) * 136 + vcol) = vreg[it];
    }
    __syncthreads();  // staging visible

    // prefetch next chunk into regs (overlaps with compute below)
    if (!last) {
      const int c1 = c0 + 128;
#pragma unroll
      for (int it = 0; it < 4; it++) {
        kreg[it] = *(const f16x8*)(kgbase + (size_t)(c1 + it * 32 + krow) * 256);
        vreg[it] = *(const f16x8*)(vgbase + it * 16 * 2048 + c1);
      }
    }

    // ---- S^T tiles: A = K rows from LDS, B = Q frag ----
    f32x4 st[8];
#pragma unroll
    for (int j = 0; j < 8; j++) {
      const f16* kp = Ks + (j * 16 + lc) * 72 + lr * 8;
      f16x8 ka0 = *(const f16x8*)(kp);
      f16x8 ka1 = *(const f16x8*)(kp + 32);
      f32x4 s = (f32x4){0.f, 0.f, 0.f, 0.f};
      s = __builtin_amdgcn_mfma_f32_16x16x32_f16(ka0, qf0, s, 0, 0, 0);
      s = __builtin_amdgcn_mfma_f32_16x16x32_f16(ka1, qf1, s, 0, 0, 0);
      st[j] = s;
    }

    // ---- causal mask (only last chunk crosses the diagonal) ----
    if (last) {
#pragma unroll
      for (int j = 0; j < 8; j++)
#pragma unroll
        for (int r = 0; r < 4; r++)
          if (c0 + j * 16 + lr * 4 + r > trow) st[j][r] = -3e38f;
    }

    // ---- chunk max: in-lane over 32 regs + 2 shuffles ----
    float mc = -3e38f;
#pragma unroll
    for (int j = 0; j < 8; j++)
      mc = fmaxf(mc, fmaxf(fmaxf(st[j][0], st[j][1]), fmaxf(st[j][2], st[j][3])));
    mc = fmaxf(mc, __shfl_xor(mc, 16));
    mc = fmaxf(mc, __shfl_xor(mc, 32));
    const float mn = fmaxf(m_run, mc);
    const float alpha = __builtin_amdgcn_exp2f(m_run - mn);
    m_run = mn;

    // ---- exp2, packed P^T stores (b64, 2-way = free), in-lane sum ----
    float ls = 0.f;
#pragma unroll
    for (int j = 0; j < 8; j++) {
      f16x4 pv;
#pragma unroll
      for (int r = 0; r < 4; r++) {
        float e = __builtin_amdgcn_exp2f(st[j][r] - mn);
        ls += e;
        pv[r] = (f16)e;
      }
      *(f16x4*)(Pw + lc * 136 + j * 16 + lr * 4) = pv;  // P^T[t=lc][s]
    }
    ls += __shfl_xor(ls, 16);
    ls += __shfl_xor(ls, 32);
    l_run = l_run * alpha + ls;
#pragma unroll
    for (int jo = 0; jo < 4; jo++) accO[jo] *= alpha;

    // ---- O^T += V^T * P^T : A = V^T frags (LDS), B = P^T (wave-private) ----
#pragma unroll
    for (int kkt = 0; kkt < 4; kkt++) {
      f16x8 pb = *(const f16x8*)(Pw + lc * 136 + kkt * 32 + lr * 8);
#pragma unroll
      for (int jo = 0; jo < 4; jo++) {
        f16x8 va = *(const f16x8*)(Vs + (jo * 16 + lc) * 136 + kkt * 32 + lr * 8);
        accO[jo] = __builtin_amdgcn_mfma_f32_16x16x32_f16(va, pb, accO[jo], 0, 0, 0);
      }
    }
  }

  // ---- epilogue: O^T lane holds col t, rows d = jo*16+lr*4+r ----
  const float inv = 1.f / l_run;
#pragma unroll
  for (int jo = 0; jo < 4; jo++) {
    f16x4 hi4, lo4;
#pragma unroll
    for (int r = 0; r < 4; r++) {
      float o = accO[jo][r] * inv;
      f16 hv = (f16)o;
      hi4[r] = hv;
      lo4[r] = (f16)(o - (float)hv);
    }
    const size_t idx = (size_t)trow * 1024 + h * 64 + jo * 16 + lr * 4;
    *(f16x4*)(ahi + idx) = hi4;
    *(f16x4*)(alo + idx) = lo4;
  }
}

// ---------------- routing: fp32 norm + gate + top2, compaction --------------
__global__ void routing_kernel(const float* __restrict__ resA,
                               const float* __restrict__ postw,
                               const float* __restrict__ gw,
                               int* __restrict__ counts, int* __restrict__ perm,
                               float* __restrict__ rw) {
  const int t = blockIdx.x * 4 + (threadIdx.x >> 6);
  const int lane = threadIdx.x & 63;
  const float* x = resA + (size_t)t * 1024;
  float v[16]; float ss = 0.f;
#pragma unroll
  for (int j = 0; j < 16; j++) { float a = x[lane + 64 * j]; v[j] = a; ss += a * a; }
#pragma unroll
  for (int m = 1; m < 64; m <<= 1) ss += __shfl_xor(ss, m);
  const float rs = rsqrtf(ss * (1.f / 1024.f) + 1e-5f);
#pragma unroll
  for (int j = 0; j < 16; j++) v[j] *= rs * postw[lane + 64 * j];
  float lg[8];
#pragma unroll
  for (int e = 0; e < 8; e++) {
    float p = 0.f;
    const float* g = gw + (size_t)e * 1024;
#pragma unroll
    for (int j = 0; j < 16; j++) p += v[j] * g[lane + 64 * j];
#pragma unroll
    for (int m = 1; m < 64; m <<= 1) p += __shfl_xor(p, m);
    lg[e] = p;
  }
  if (lane == 0) {
    int e0 = 0; float b0 = lg[0];
#pragma unroll
    for (int e = 1; e < 8; e++) if (lg[e] > b0) { b0 = lg[e]; e0 = e; }
    int e1 = -1; float b1 = -3e38f;
#pragma unroll
    for (int e = 0; e < 8; e++) if (e != e0 && lg[e] > b1) { b1 = lg[e]; e1 = e; }
    const float w0 = 1.f / (1.f + expf(b1 - b0));  // p0/(p0+p1)
    const float w1 = 1.f - w0;
    int p0 = atomicAdd(&counts[e0], 1);
    perm[e0 * 2048 + p0] = t * 2;
    int p1 = atomicAdd(&counts[e1], 1);
    perm[e1 * 2048 + p1] = t * 2 + 1;
    rw[t * 2] = w0;
    rw[t * 2 + 1] = w1;
  }
}

// ---------------- silu(g)*u ----------------
__global__ void silu_mul_kernel(const f16* __restrict__ gu, f16* __restrict__ outp, int lgN) {
  const int N = 1 << lgN;
  const size_t i4 = ((size_t)blockIdx.x * 256 + threadIdx.x) * 4;
  const size_t r = i4 >> lgN;
  const int c = (int)(i4 & (N - 1));
  const f16* gp = gu + r * (size_t)(2 * N) + c;
  f16x4 g = *(const f16x4*)gp;
  f16x4 u = *(const f16x4*)(gp + N);
  f16x4 o;
#pragma unroll
  for (int x = 0; x < 4; x++) {
    float gg = (float)g[x], uu = (float)u[x];
    o[x] = (f16)(gg / (1.f + __expf(-gg)) * uu);
  }
  *(f16x4*)(outp + r * (size_t)N + c) = o;
}

// ---------------- final: out += w0*eo[2t] + w1*eo[2t+1] ----------------
__global__ void final_add_kernel(float* __restrict__ outp, const f16* __restrict__ eo,
                                 const float* __restrict__ rw) {
  const size_t i4 = ((size_t)blockIdx.x * 256 + threadIdx.x) * 4;
  const int t = (int)(i4 >> 10);
  const int c = (int)(i4 & 1023);
  const float w0 = rw[2 * t], w1 = rw[2 * t + 1];
  f16x4 a = *(const f16x4*)(eo + ((size_t)(2 * t)) * 1024 + c);
  f16x4 b = *(const f16x4*)(eo + ((size_t)(2 * t + 1)) * 1024 + c);
  float4 o = *(float4*)(outp + i4);
  o.x += w0 * (float)a[0] + w1 * (float)b[0];
  o.y += w0 * (float)a[1] + w1 * (float)b[1];
  o.z += w0 * (float)a[2] + w1 * (float)b[2];
  o.w += w0 * (float)a[3] + w1 * (float)b[3];
  *(float4*)(outp + i4) = o;
}

extern "C" void kernel_launch(void* const* d_in, const int* in_sizes, int n_in,
                              void* d_out, int out_size, void* d_ws, size_t ws_size,
                              hipStream_t stream) {
  const int* positions = (const int*)d_in[0];
  const float* hidden = (const float*)d_in[1];
  const float* in_ln = (const float*)d_in[2];
  const float* post_ln = (const float*)d_in[3];
  const float* res_ln = (const float*)d_in[4];
  const float* qkv_w = (const float*)d_in[5];
  const float* o_w = (const float*)d_in[6];
  const float* gate_w = (const float*)d_in[7];
  const float* ws_w = (const float*)d_in[8];
  const float* w2s_w = (const float*)d_in[9];
  const float* w13_w = (const float*)d_in[10];
  const float* w2_w = (const float*)d_in[11];
  float* out = (float*)d_out;

  char* p = (char*)d_ws;
  auto alloc = [&](size_t b) { void* r = (void*)p; p += (b + 255) & ~(size_t)255; return r; };

  f16* wqkv = (f16*)alloc((size_t)1536 * 1024 * 2);
  f16* woh  = (f16*)alloc((size_t)1024 * 1024 * 2);
  f16* wol  = (f16*)alloc((size_t)1024 * 1024 * 2);
  f16* wws  = (f16*)alloc((size_t)8 * 4096 * 1024 * 2);
  f16* ww2  = (f16*)alloc((size_t)8 * 1024 * 2048 * 2);
  f16* w13  = (f16*)alloc((size_t)2048 * 1024 * 2);
  f16* w2c  = (f16*)alloc((size_t)1024 * 1024 * 2);
  f16* hn   = (f16*)alloc((size_t)2048 * 1024 * 2);
  float* qkvf = (float*)alloc((size_t)2048 * 1536 * 4);
  f16* qr = (f16*)alloc((size_t)2048 * 1024 * 2);
  f16* kr = (f16*)alloc((size_t)2048 * 256 * 2);
  f16* vt = (f16*)alloc((size_t)256 * 2048 * 2);
  f16* ath = (f16*)alloc((size_t)2048 * 1024 * 2);
  f16* atl = (f16*)alloc((size_t)2048 * 1024 * 2);
  float* resA = (float*)alloc((size_t)2048 * 1024 * 4);
  f16* rn = (f16*)alloc((size_t)2048 * 1024 * 2);
  f16* mn = (f16*)alloc((size_t)2048 * 1024 * 2);
  f16* gu13 = (f16*)alloc((size_t)2048 * 2048 * 2);
  f16* act13 = (f16*)alloc((size_t)2048 * 1024 * 2);
  f16* gum = (f16*)alloc((size_t)4096 * 4096 * 2);
  f16* actm = (f16*)alloc((size_t)4096 * 2048 * 2);
  f16* eo = (f16*)alloc((size_t)4096 * 1024 * 2);
  float* rw = (float*)alloc((size_t)4096 * 4);
  int* counts = (int*)alloc(256);
  int* perm = (int*)alloc((size_t)8 * 2048 * 4);

  // weight conversions (ws is re-poisoned before every timed launch)
  cvt_f16_kernel<<<dim3(1536 * 1024 / 1024), dim3(256), 0, stream>>>(qkv_w, wqkv);
  cvt_f16_kernel<<<dim3(8 * 4096 * 1024 / 1024), dim3(256), 0, stream>>>(ws_w, wws);
  cvt_f16_kernel<<<dim3(8 * 1024 * 2048 / 1024), dim3(256), 0, stream>>>(w2s_w, ww2);
  cvt_f16_kernel<<<dim3(2048 * 1024 / 1024), dim3(256), 0, stream>>>(w13_w, w13);
  cvt_f16_kernel<<<dim3(1024 * 1024 / 1024), dim3(256), 0, stream>>>(w2_w, w2c);
  cvt_f16x2_kernel<<<dim3(1024 * 1024 / 1024), dim3(256), 0, stream>>>(o_w, woh, wol);
  hipMemsetAsync(counts, 0, 256, stream);

  // attention path
  rmsnorm_kernel<<<dim3(512), dim3(256), 0, stream>>>(hidden, in_ln, hn);
  gemm_f16_kernel<0, 64><<<dim3(24, 16), dim3(256), 0, stream>>>(
      hn, wqkv, (void*)qkvf, (const float*)nullptr, 2048, 1536, 1024);
  rope_kernel<<<dim3(3, 2048), dim3(256), 0, stream>>>(qkvf, positions, qr, kr);
  vtrans_kernel<<<dim3(32, 4), dim3(256), 0, stream>>>(qkvf, vt);
  attn_kernel<<<dim3(32, 16), dim3(256), 0, stream>>>(qr, kr, vt, ath, atl);
  gemm_f16x2_add_kernel<<<dim3(16, 16), dim3(256), 0, stream>>>(
      ath, atl, woh, wol, resA, hidden, 2048, 1024, 1024);

  // norms + routing off residual_attn
  rmsnorm_dual_kernel<<<dim3(512), dim3(256), 0, stream>>>(resA, res_ln, post_ln, rn, mn);
  routing_kernel<<<dim3(512), dim3(256), 0, stream>>>(resA, post_ln, gate_w, counts, perm, rw);

  // residual MLP -> d_out holds residual_mlp
  gemm_f16_kernel<2, 64><<<dim3(32, 16), dim3(256), 0, stream>>>(
      rn, w13, (void*)gu13, (const float*)nullptr, 2048, 2048, 1024);
  silu_mul_kernel<<<dim3(2048 * 1024 / 1024), dim3(256), 0, stream>>>(gu13, act13, 10);
  gemm_f16_kernel<1, 64><<<dim3(16, 16), dim3(256), 0, stream>>>(
      act13, w2c, (void*)out, resA, 2048, 1024, 1024);

  // MoE (top-2 sparse)
  gemm_moe_kernel<1, 128><<<dim3(32, 16, 8), dim3(256), 0, stream>>>(
      mn, wws, gum, perm, counts, 4096, 1024, (size_t)4096 * 1024);
  silu_mul_kernel<<<dim3(4096 * 2048 / 1024), dim3(256), 0, stream>>>(gum, actm, 11);
  gemm_moe_kernel<0, 64><<<dim3(16, 16, 8), dim3(256), 0, stream>>>(
      actm, ww2, eo, perm, counts, 1024, 2048, (size_t)1024 * 2048);
  final_add_kernel<<<dim3(2048 * 1024 / 1024), dim3(256), 0, stream>>>(out, eo, rw);
}